// Round 7
// baseline (759.394 us; speedup 1.0000x reference)
//
#include <hip/hip_runtime.h>
#include <cstdint>
#include <cstddef>

#define DEV __device__ __forceinline__
#define AS1 __attribute__((address_space(1)))
#define AS3 __attribute__((address_space(3)))

typedef unsigned short u16;
typedef unsigned char u8;
typedef long long ll;

typedef __attribute__((ext_vector_type(8))) __bf16 bf16x8;
typedef __attribute__((ext_vector_type(8))) unsigned short u16x8;
typedef __attribute__((ext_vector_type(4))) float f32x4;

static constexpr int SEQ  = 720;
static constexpr int ENC  = 862;
static constexpr int NTOK = 866;            // ENC + MARK
static constexpr int DM   = 256;
static constexpr int G16  = 16;             // B * T_SCALES
static constexpr int MTOT = G16 * NTOK;     // 13856
static constexpr int KPAD = 768;            // SEQ padded to multiple of 64
static constexpr int SPAD = 896;            // 866 keys padded to multiple of 32
static constexpr int TCH  = 15;             // time chunks for stats (720 = 15*48)
static constexpr float SC2 = 0.17677669529663689f * 1.4426950408889634f; // scale*log2e

DEV float b2f(u16 v){ union { unsigned u; float f; } x; x.u = ((unsigned)v) << 16; return x.f; }
DEV u16 f2b(float f){ union { float f; unsigned u; } x; x.f = f;
  unsigned r = x.u + 0x7fffu + ((x.u >> 16) & 1u); return (u16)(r >> 16); }
DEV bf16x8 as_bf(u16x8 v){ return __builtin_bit_cast(bf16x8, v); }

// async global->LDS, 16B per lane; LDS base wave-uniform
DEV void g2l(const u16* g, u16* l){
  __builtin_amdgcn_global_load_lds((AS1 void*)g, (AS3 void*)l, 16, 0, 0);
}

// XCD-aware remap: XCD (L%8) owns a contiguous band of work-items
DEV int xcd_work(){
  int L = blockIdx.y * gridDim.x + blockIdx.x;
  int T = gridDim.x * gridDim.y;
  int x = L & 7, k = L >> 3;
  int q = T >> 3, r = T & 7;
  int mn = x < r ? x : r;
  return x*q + mn + k;
}

// ------------------------------------------------------------------
struct CvtJobs {
  const float* src[10];
  u16* dst[10];
  int n[10];
  int per[10];
  ll stride[10];
};
__global__ __launch_bounds__(256) void cvt_multi(CvtJobs J)
{
  int j = blockIdx.y;
  const float* s = J.src[j];
  u16* d = J.dst[j];
  int n = J.n[j], per = J.per[j];
  ll st = J.stride[j];
  for (int i = blockIdx.x*256 + threadIdx.x; i < n; i += gridDim.x*256) {
    ll di = per ? ((ll)(i/per)*st + (i%per)) : (ll)i;
    d[di] = f2b(s[i]);
  }
}

__global__ __launch_bounds__(256) void pack_bqkv(const float* __restrict__ bq,
                                                 const float* __restrict__ bk,
                                                 const float* __restrict__ bv,
                                                 float* __restrict__ out)
{
  int idx = blockIdx.x*256 + threadIdx.x;
  if (idx >= 1536) return;
  int l = idx / 768, j = idx % 768;
  float v;
  if (j < 256)      v = bq[l*256 + j];
  else if (j < 512) v = bk[l*256 + j - 256];
  else              v = bv[l*256 + j - 512];
  out[idx] = v;
}

// ------------------------------------------------------------------
// per-(group, column) mean/std over SEQ, two-pass deterministic.
// ------------------------------------------------------------------
__global__ __launch_bounds__(256) void stats_part(const float* __restrict__ x,
                                                  float2* __restrict__ part)
{
  int g  = blockIdx.z;
  int tc = blockIdx.y;
  int c  = (blockIdx.x << 8) + threadIdx.x;
  float s = 0.f, q = 0.f;
  if (c < ENC) {
    const float* xp = x + ((ll)g * SEQ + tc * 48) * ENC + c;
    #pragma unroll 8
    for (int t = 0; t < 48; ++t) {
      float v = xp[(ll)t * ENC];
      s += v; q += v * v;
    }
  }
  part[(((ll)g * TCH + tc) * 4 + blockIdx.x) * 256 + threadIdx.x] = make_float2(s, q);
}

__global__ __launch_bounds__(256) void stats_reduce(const float2* __restrict__ part,
                                                    float* __restrict__ meanp,
                                                    float* __restrict__ stdp)
{
  int g  = blockIdx.x >> 2;
  int cc = blockIdx.x & 3;
  int c  = (cc << 8) + threadIdx.x;
  if (c >= ENC) return;
  float s = 0.f, q = 0.f;
  #pragma unroll
  for (int t = 0; t < TCH; ++t) {
    float2 p = part[(((ll)g * TCH + t) * 4 + cc) * 256 + threadIdx.x];
    s += p.x; q += p.y;
  }
  float mn  = s * (1.f / SEQ);
  float var = q * (1.f / SEQ) - mn * mn;
  var = var < 0.f ? 0.f : var;
  meanp[g * ENC + c] = mn;
  stdp [g * ENC + c] = sqrtf(var + 1e-5f);
}

// ------------------------------------------------------------------
__global__ __launch_bounds__(256) void build_xin(const float* __restrict__ x,
                                                 const float* __restrict__ xm,
                                                 const float* __restrict__ meanp,
                                                 const float* __restrict__ stdp,
                                                 u16* __restrict__ xin)
{
  int g  = blockIdx.z;
  int c0 = blockIdx.x << 5, s0 = blockIdx.y << 5;
  __shared__ float tl[32][33];
  __shared__ float mn[32], isd[32];
  int tid = threadIdx.x;
  if (tid < 32) {
    int c = c0 + tid;
    float m = 0.f, s = 1.f;
    if (c < ENC) { m = meanp[g*ENC + c]; s = stdp[g*ENC + c]; }
    mn[tid] = m; isd[tid] = 1.f / s;
  }
  __syncthreads();
  int ci = tid & 31, r = tid >> 5;
  #pragma unroll
  for (int p = 0; p < 4; ++p) {
    int sl = r + (p << 3);
    int s = s0 + sl, c = c0 + ci;
    float v = 0.f;
    if (s < SEQ && c < NTOK) {
      if (c < ENC) v = (x[((ll)g*SEQ + s)*ENC + c] - mn[ci]) * isd[ci];
      else         v = xm[((ll)g*SEQ + s)*4 + (c - ENC)];
    }
    tl[sl][ci] = v;
  }
  __syncthreads();
  int si = tid & 31;
  #pragma unroll
  for (int p = 0; p < 4; ++p) {
    int cl = r + (p << 3);
    int c = c0 + cl;
    if (c < NTOK) xin[((ll)g*NTOK + c)*KPAD + s0 + si] = f2b(tl[si][cl]);
  }
}

// ------------------------------------------------------------------
__global__ __launch_bounds__(256) void pack_embedw(const float* __restrict__ ew,
                                                   u16* __restrict__ wp)
{
  int row = blockIdx.x;
  for (int c = threadIdx.x; c < KPAD; c += 256)
    wp[row*KPAD + c] = (c < SEQ) ? f2b(ew[row*SEQ + c]) : (u16)0;
}

// ------------------------------------------------------------------
__global__ __launch_bounds__(256) void transpose_v(const u16* __restrict__ v, int ldv,
                                                   u16* __restrict__ vT)
{
  int g = blockIdx.z;
  int d0 = blockIdx.x << 5, s0 = blockIdx.y << 5;
  __shared__ u16 tl[32][33];
  int tid = threadIdx.x;
  int di = tid & 31, r = tid >> 5;
  #pragma unroll
  for (int p = 0; p < 4; ++p) {
    int sl = r + (p << 3);
    int s = s0 + sl;
    u16 val = 0;
    if (s < NTOK) val = v[((ll)g*NTOK + s)*ldv + d0 + di];
    tl[sl][di] = val;
  }
  __syncthreads();
  int si = tid & 31;
  #pragma unroll
  for (int p = 0; p < 4; ++p) {
    int dl = r + (p << 3);
    vT[((ll)g*DM + d0 + dl)*SPAD + s0 + si] = tl[si][dl];
  }
}

// ------------------------------------------------------------------
// flash attention, fixed-max softmax (Q pre-scaled by scale*log2e).
// ------------------------------------------------------------------
__global__ __launch_bounds__(256) void flash_attn(const u16* __restrict__ qb,
                                                  const u16* __restrict__ kb,
                                                  int ldqk,
                                                  const u16* __restrict__ vT,
                                                  u16* __restrict__ attb)
{
  const int w = xcd_work();
  const int gh = w / 7;
  const int g = gh >> 3, h = gh & 7;
  const int q0 = (w % 7) * 128;
  const int tid = threadIdx.x, wv = tid >> 6, lane = tid & 63;
  const int q4 = lane >> 4, c16 = lane & 15;
  constexpr int PLD = 136;

  __shared__ __attribute__((aligned(16))) u16 Qs[128*32];
  __shared__ __attribute__((aligned(16))) u16 Ks[128*32];
  __shared__ __attribute__((aligned(16))) u16 Vs[32*PLD];
  __shared__ __attribute__((aligned(16))) u16 Ps[4][32*PLD];

  {
    int r = tid >> 1, sg = (tid & 1) << 4;
    int row = q0 + r; if (row > NTOK-1) row = NTOK-1;
    const u16* src = qb + ((ll)(g*NTOK + row))*ldqk + h*32 + sg;
    *(uint4*)&Qs[r*32 + sg]     = *(const uint4*)src;
    *(uint4*)&Qs[r*32 + sg + 8] = *(const uint4*)(src + 8);
  }
  __syncthreads();

  bf16x8 qf[2];
  qf[0] = as_bf(*(const u16x8*)&Qs[(wv*32 +      c16)*32 + q4*8]);
  qf[1] = as_bf(*(const u16x8*)&Qs[(wv*32 + 16 + c16)*32 + q4*8]);

  float lsum[2][4] = {{0,0,0,0},{0,0,0,0}};
  f32x4 oacc[2][2];
  oacc[0][0] = (f32x4){0,0,0,0}; oacc[0][1] = (f32x4){0,0,0,0};
  oacc[1][0] = (f32x4){0,0,0,0}; oacc[1][1] = (f32x4){0,0,0,0};

  for (int kt = 0; kt < 7; ++kt) {
    const int k0 = kt * 128;
    if (kt) __syncthreads();
    {
      int r = tid >> 1, sg = (tid & 1) << 4;
      int row = k0 + r; if (row > NTOK-1) row = NTOK-1;
      const u16* src = kb + ((ll)(g*NTOK + row))*ldqk + h*32 + sg;
      *(uint4*)&Ks[r*32 + sg]     = *(const uint4*)src;
      *(uint4*)&Ks[r*32 + sg + 8] = *(const uint4*)(src + 8);
    }
    {
      int e = tid >> 3, sg = (tid & 7) << 4;
      const u16* src = vT + ((ll)(g*DM + h*32 + e))*SPAD + k0 + sg;
      *(uint4*)&Vs[e*PLD + sg]     = *(const uint4*)src;
      *(uint4*)&Vs[e*PLD + sg + 8] = *(const uint4*)(src + 8);
    }
    __syncthreads();

    f32x4 s[2][8];
    #pragma unroll
    for (int i = 0; i < 2; ++i)
      #pragma unroll
      for (int j = 0; j < 8; ++j) s[i][j] = (f32x4){0,0,0,0};
    #pragma unroll
    for (int j = 0; j < 8; ++j) {
      bf16x8 kf = as_bf(*(const u16x8*)&Ks[(j*16 + c16)*32 + q4*8]);
      s[0][j] = __builtin_amdgcn_mfma_f32_16x16x32_bf16(qf[0], kf, s[0][j], 0, 0, 0);
      s[1][j] = __builtin_amdgcn_mfma_f32_16x16x32_bf16(qf[1], kf, s[1][j], 0, 0, 0);
    }
    if (kt == 6) {
      #pragma unroll
      for (int j = 0; j < 8; ++j) {
        if (k0 + j*16 + c16 >= NTOK) {
          #pragma unroll
          for (int r = 0; r < 4; ++r) { s[0][j][r] = -1e30f; s[1][j][r] = -1e30f; }
        }
      }
    }

    #pragma unroll
    for (int i = 0; i < 2; ++i)
      #pragma unroll
      for (int j = 0; j < 8; ++j)
        #pragma unroll
        for (int r = 0; r < 4; ++r) {
          float p = exp2f(s[i][j][r]);
          lsum[i][r] += p;
          unsigned u = __builtin_bit_cast(unsigned, p);
          Ps[wv][(i*16 + q4*4 + r)*PLD + j*16 + c16] = (u16)(u >> 16);
        }

    #pragma unroll
    for (int kk = 0; kk < 4; ++kk) {
      bf16x8 af0 = as_bf(*(const u16x8*)&Ps[wv][(     c16)*PLD + kk*32 + q4*8]);
      bf16x8 af1 = as_bf(*(const u16x8*)&Ps[wv][(16 + c16)*PLD + kk*32 + q4*8]);
      bf16x8 b0  = as_bf(*(const u16x8*)&Vs[(     c16)*PLD + kk*32 + q4*8]);
      bf16x8 b1  = as_bf(*(const u16x8*)&Vs[(16 + c16)*PLD + kk*32 + q4*8]);
      oacc[0][0] = __builtin_amdgcn_mfma_f32_16x16x32_bf16(af0, b0, oacc[0][0], 0, 0, 0);
      oacc[0][1] = __builtin_amdgcn_mfma_f32_16x16x32_bf16(af0, b1, oacc[0][1], 0, 0, 0);
      oacc[1][0] = __builtin_amdgcn_mfma_f32_16x16x32_bf16(af1, b0, oacc[1][0], 0, 0, 0);
      oacc[1][1] = __builtin_amdgcn_mfma_f32_16x16x32_bf16(af1, b1, oacc[1][1], 0, 0, 0);
    }
  }

  float linv[2][4];
  #pragma unroll
  for (int i = 0; i < 2; ++i)
    #pragma unroll
    for (int r = 0; r < 4; ++r) {
      float t = lsum[i][r];
      t += __shfl_xor(t, 1, 64);
      t += __shfl_xor(t, 2, 64);
      t += __shfl_xor(t, 4, 64);
      t += __shfl_xor(t, 8, 64);
      linv[i][r] = 1.f / t;
    }
  #pragma unroll
  for (int i = 0; i < 2; ++i)
    #pragma unroll
    for (int jn = 0; jn < 2; ++jn)
      #pragma unroll
      for (int r = 0; r < 4; ++r) {
        int row = q0 + wv*32 + i*16 + q4*4 + r;
        if (row < NTOK)
          attb[((ll)(g*NTOK + row))*DM + h*32 + jn*16 + c16] =
            f2b(oacc[i][jn][r] * linv[i][r]);
      }
}

// ------------------------------------------------------------------
__global__ __launch_bounds__(256) void ln_rows(const u16* __restrict__ in1,
                                               const u16* __restrict__ in2,
                                               int ld1, int ld2,
                                               const float* __restrict__ gamma,
                                               const float* __restrict__ beta,
                                               u16* __restrict__ out, int ldo, int Mrows)
{
  int row = blockIdx.x*4 + (threadIdx.x >> 6);
  int lane = threadIdx.x & 63;
  if (row >= Mrows) return;
  float xv[4];
  ushort4 a = *(const ushort4*)(in1 + (ll)row*ld1 + lane*4);
  xv[0]=b2f(a.x); xv[1]=b2f(a.y); xv[2]=b2f(a.z); xv[3]=b2f(a.w);
  if (in2) {
    ushort4 b = *(const ushort4*)(in2 + (ll)row*ld2 + lane*4);
    xv[0]-=b2f(b.x); xv[1]-=b2f(b.y); xv[2]-=b2f(b.z); xv[3]-=b2f(b.w);
  }
  float s = xv[0]+xv[1]+xv[2]+xv[3];
  #pragma unroll
  for (int o = 32; o > 0; o >>= 1) s += __shfl_xor(s, o, 64);
  float mean = s * (1.f/256.f);
  float d0=xv[0]-mean, d1=xv[1]-mean, d2=xv[2]-mean, d3=xv[3]-mean;
  float q = d0*d0 + d1*d1 + d2*d2 + d3*d3;
  #pragma unroll
  for (int o = 32; o > 0; o >>= 1) q += __shfl_xor(q, o, 64);
  float rstd = 1.f / sqrtf(q * (1.f/256.f) + 1e-5f);
  float4 gv = *(const float4*)(gamma + lane*4);
  float4 bb = *(const float4*)(beta  + lane*4);
  ushort4 o4;
  o4.x = f2b(d0*rstd*gv.x + bb.x);
  o4.y = f2b(d1*rstd*gv.y + bb.y);
  o4.z = f2b(d2*rstd*gv.z + bb.z);
  o4.w = f2b(d3*rstd*gv.w + bb.w);
  *(ushort4*)(out + (ll)row*ldo + lane*4) = o4;
}

// ------------------------------------------------------------------
__global__ __launch_bounds__(256) void final_combine(const u16* __restrict__ outF,
                                                     const float* __restrict__ meanp,
                                                     const float* __restrict__ stdp,
                                                     float* __restrict__ dout)
{
  int b = blockIdx.z;
  int c0 = blockIdx.x << 5, s0 = blockIdx.y << 5;
  __shared__ float tl[32][33];
  int tid = threadIdx.x;
  int si = tid & 31, r = tid >> 5;
  #pragma unroll
  for (int p = 0; p < 4; ++p) {
    int cl = r + (p << 3);
    int c = c0 + cl, s = s0 + si;
    float accv = 0.f;
    #pragma unroll
    for (int t = 0; t < 2; ++t) {
      int g = b*2 + t;
      if (c < ENC && s < SEQ) {
        float v = b2f(outF[((ll)(g*NTOK + c))*SEQ + s]);
        accv += 0.5f * (v * stdp[g*ENC + c] + meanp[g*ENC + c]);
      }
    }
    tl[cl][si] = accv;
  }
  __syncthreads();
  int ci = tid & 31;
  #pragma unroll
  for (int p = 0; p < 4; ++p) {
    int sl = r + (p << 3);
    int s = s0 + sl, c = c0 + ci;
    if (s < SEQ && c < ENC)
      dout[((ll)b*SEQ + s)*ENC + c] = tl[ci][sl];
  }
}

// ------------------------------------------------------------------
// Pipelined 64x64-tile NT GEMM, K-step 64 (two 32-wide panels),
// double-buffered LDS, raw s_barrier + counted vmcnt (T3/T4 recipe).
// Conflict-free XOR swizzle both sides (rule #21, verified r5: 0 conflicts).
// NB=1: modes 0 store / 1 gelu / 2 store+sub / 5 qkv. 32 KiB, 5 blk/CU.
// NB=2: 48 KiB, 3 blk/CU (used for W3/W4: N=256 keeps block count high).
// ------------------------------------------------------------------
template<int NB>
__global__ __launch_bounds__(256, NB == 1 ? 5 : 3) void gemm64(
    const u16* __restrict__ A, const u16* __restrict__ B0, const u16* __restrict__ B1,
    const float* __restrict__ bias0, const float* __restrict__ bias1,
    u16* __restrict__ C,
    const u16* __restrict__ aux1, u16* __restrict__ aux2, const u16* __restrict__ sub,
    int M, int N, int K, int lda, int ldb, int ldc, int ld1, int ld2, int ldsub, int mode)
{
  // [buf p][panel c] tiles of 64 rows x 32 cols, row-major ld=32
  __shared__ __attribute__((aligned(16))) u16 S[8192 * (1 + NB)];

  const int tid  = threadIdx.x;
  const int wv   = tid >> 6;
  const int lane = tid & 63;
  const int q4   = lane >> 4;
  const int c16  = lane & 15;

  const int w  = xcd_work();
  const int n0 = (w % gridDim.x) * 64;
  const int m0 = (w / gridDim.x) * 64;
  const int wm = (wv >> 1) * 32;
  const int wn = (wv & 1) * 32;

  // staging: 16 rows x 64 B per g2l; source chunk pre-swizzled so the
  // linear LDS write produces the XOR-swizzled layout
  const int lrow = lane >> 2;                                   // 0..15
  const int lcol = (((lane & 3) ^ ((lrow >> 1) & 3)) << 3);     // u16 offset

  int arow = m0 + wv*16 + lrow; if (arow >= M) arow = M-1;
  int brow = n0 + wv*16 + lrow; if (brow >= N) brow = N-1;
  const u16* pa  = A  + (ll)arow*lda + lcol;
  const u16* pb0 = B0 + (ll)brow*ldb + lcol;
  const u16* pb1 = (NB == 2) ? B1 + (ll)brow*ldb + lcol : nullptr;

  f32x4 acc0[2][2];
  f32x4 acc1[2][2];
  #pragma unroll
  for (int i = 0; i < 2; ++i)
    #pragma unroll
    for (int j = 0; j < 2; ++j) {
      acc0[i][j] = (f32x4){0,0,0,0};
      if constexpr (NB == 2) acc1[i][j] = (f32x4){0,0,0,0};
    }

  const int nk = K >> 6;
  auto issue = [&](int kt2, int p) {
    const int ko = kt2 * 64;
    #pragma unroll
    for (int c = 0; c < 2; ++c) {
      g2l(pa  + ko + c*32, &S[(p*2 + c)*2048 + (wv*16)*32]);
      g2l(pb0 + ko + c*32, &S[8192 + (p*2 + c)*2048 + (wv*16)*32]);
      if constexpr (NB == 2)
        g2l(pb1 + ko + c*32, &S[16384 + (p*2 + c)*2048 + (wv*16)*32]);
    }
  };

  issue(0, 0);
  for (int kt = 0; kt < nk; ++kt) {
    const int p = kt & 1;
    if (kt + 1 < nk) {
      issue(kt + 1, p ^ 1);
      // counted wait: just-issued loads (4 or 6) stay in flight
      if constexpr (NB == 1) asm volatile("s_waitcnt vmcnt(4)" ::: "memory");
      else                   asm volatile("s_waitcnt vmcnt(6)" ::: "memory");
    } else {
      asm volatile("s_waitcnt vmcnt(0)" ::: "memory");
    }
    __builtin_amdgcn_s_barrier();
    asm volatile("" ::: "memory");

    const int sw = ((q4 ^ ((c16 >> 1) & 3)) << 3);  // swizzled read chunk
    #pragma unroll
    for (int c = 0; c < 2; ++c) {
      const u16* as_ = &S[(p*2 + c)*2048];
      const u16* b0s = &S[8192 + (p*2 + c)*2048];
      bf16x8 af[2], bfv[2];
      #pragma unroll
      for (int i = 0; i < 2; ++i)
        af[i] = as_bf(*(const u16x8*)&as_[(wm + i*16 + c16)*32 + sw]);
      #pragma unroll
      for (int j = 0; j < 2; ++j)
        bfv[j] = as_bf(*(const u16x8*)&b0s[(wn + j*16 + c16)*32 + sw]);
      #pragma unroll
      for (int i = 0; i < 2; ++i)
        #pragma unroll
        for (int j = 0; j < 2; ++j)
          acc0[i][j] = __builtin_amdgcn_mfma_f32_16x16x32_bf16(af[i], bfv[j], acc0[i][j], 0, 0, 0);
      if constexpr (NB == 2) {
        const u16* b1s = &S[16384 + (p*2 + c)*2048];
        bf16x8 b1v[2];
        #pragma unroll
        for (int j = 0; j < 2; ++j)
          b1v[j] = as_bf(*(const u16x8*)&b1s[(wn + j*16 + c16)*32 + sw]);
        #pragma unroll
        for (int i = 0; i < 2; ++i)
          #pragma unroll
          for (int j = 0; j < 2; ++j)
            acc1[i][j] = __builtin_amdgcn_mfma_f32_16x16x32_bf16(af[i], b1v[j], acc1[i][j], 0, 0, 0);
      }
    }

    asm volatile("s_waitcnt lgkmcnt(0)" ::: "memory");
    __builtin_amdgcn_s_barrier();
  }

  #pragma unroll
  for (int i = 0; i < 2; ++i) {
    #pragma unroll
    for (int j = 0; j < 2; ++j) {
      int n = n0 + wn + j*16 + c16;
      if (n >= N) continue;
      float bv0 = bias0 ? bias0[n] : 0.f;
      float bv1 = (NB == 2) ? bias1[n] : 0.f;
      int mb = m0 + wm + i*16 + q4*4;
      #pragma unroll
      for (int r = 0; r < 4; ++r) {
        int m = mb + r;
        if (m >= M) continue;
        ll ci = (ll)m*ldc + n;
        if constexpr (NB == 2) {
          float z5 = acc0[i][j][r] + bv0;
          float z6 = acc1[i][j][r] + bv1;
          float v = z6 / (1.f + expf(-z5));
          if (sub) v -= b2f(sub[(ll)m*ldsub + n]);
          C[ci] = f2b(v);
        } else {
          float x = acc0[i][j][r] + bv0;
          if (mode == 0) {
            C[ci] = f2b(x);
          } else if (mode == 1) {
            C[ci] = f2b(0.5f * x * (1.f + erff(x * 0.70710678118654752f)));
          } else if (mode == 5) {
            C[ci] = f2b(n < 256 ? x * SC2 : x);
          } else { // mode 2
            C[ci] = f2b(x);
            float xl = b2f(aux1[(ll)m*ld1 + n]);
            aux2[(ll)m*ld2 + n] = f2b(xl - x);
          }
        }
      }
    }
  }
}

// ------------------------------------------------------------------
// Register-tile dual-B NT GEMM for W5/W6: NO LDS, NO BARRIERS.
// Rationale (r2-r6 post-mortems): four schedule/LDS variants all pinned
// at ~61 us / MfmaUtil 13.5% with nothing saturated -> the 2-phase
// barrier+waitcnt convoy itself is the cost (m233: ~72% structural).
// Operands are L2-resident (B0+B1 = 1.5 MB total, A tile reused 12x),
// so load MFMA fragments directly global->VGPR (16 B offset-immediate
// loads off 6 per-lane row pointers) with a 1-step register prefetch.
// Waves never sync; latency hidden by prefetch ILP + 12 waves/CU TLP.
// Accumulation order identical to gemm64<2> (same (kt,c) sequence).
// ------------------------------------------------------------------
__global__ __launch_bounds__(256, 3) void gemm_reg_dual(
    const u16* __restrict__ A, const u16* __restrict__ B0, const u16* __restrict__ B1,
    const float* __restrict__ bias0, const float* __restrict__ bias1,
    u16* __restrict__ C, const u16* __restrict__ sub,
    int M, int N, int K, int lda, int ldb, int ldc, int ldsub)
{
  const int tid  = threadIdx.x;
  const int wv   = tid >> 6;
  const int lane = tid & 63;
  const int q4   = lane >> 4;
  const int c16  = lane & 15;

  const int w  = xcd_work();
  const int n0 = (w % gridDim.x) * 64;
  const int m0 = (w / gridDim.x) * 64;
  const int wm = (wv >> 1) * 32;
  const int wn = (wv & 1) * 32;

  // per-lane fragment row pointers (clamped), k-offset folded via imm
  int ar0 = m0 + wm + c16;      if (ar0 >= M) ar0 = M-1;
  int ar1 = m0 + wm + 16 + c16; if (ar1 >= M) ar1 = M-1;
  int br0 = n0 + wn + c16;      if (br0 >= N) br0 = N-1;
  int br1 = n0 + wn + 16 + c16; if (br1 >= N) br1 = N-1;
  const u16* pa0 = A  + (ll)ar0*lda + q4*8;
  const u16* pa1 = A  + (ll)ar1*lda + q4*8;
  const u16* p00 = B0 + (ll)br0*ldb + q4*8;
  const u16* p01 = B0 + (ll)br1*ldb + q4*8;
  const u16* p10 = B1 + (ll)br0*ldb + q4*8;
  const u16* p11 = B1 + (ll)br1*ldb + q4*8;

  f32x4 acc0[2][2], acc1[2][2];
  #pragma unroll
  for (int i = 0; i < 2; ++i)
    #pragma unroll
    for (int j = 0; j < 2; ++j) {
      acc0[i][j] = (f32x4){0,0,0,0};
      acc1[i][j] = (f32x4){0,0,0,0};
    }

  // fragment sets: [c-panel][i or j]
  u16x8 a_[2][2], x_[2][2], y_[2][2];     // current A, B0, B1
  u16x8 an[2][2], xn[2][2], yn[2][2];     // next
  auto load_all = [&](u16x8 (&aa)[2][2], u16x8 (&xx)[2][2], u16x8 (&yy)[2][2], int k0) {
    #pragma unroll
    for (int c = 0; c < 2; ++c) {
      const int o = k0 + c*32;
      aa[c][0] = *(const u16x8*)(pa0 + o);
      aa[c][1] = *(const u16x8*)(pa1 + o);
      xx[c][0] = *(const u16x8*)(p00 + o);
      xx[c][1] = *(const u16x8*)(p01 + o);
      yy[c][0] = *(const u16x8*)(p10 + o);
      yy[c][1] = *(const u16x8*)(p11 + o);
    }
  };

  const int nk = K >> 6;
  load_all(a_, x_, y_, 0);
  for (int kt = 0; kt < nk; ++kt) {
    const int k1 = (kt + 1 < nk) ? (kt + 1) * 64 : 0;  // dummy reload on last iter
    load_all(an, xn, yn, k1);
    #pragma unroll
    for (int c = 0; c < 2; ++c) {
      #pragma unroll
      for (int i = 0; i < 2; ++i)
        #pragma unroll
        for (int j = 0; j < 2; ++j) {
          acc0[i][j] = __builtin_amdgcn_mfma_f32_16x16x32_bf16(as_bf(a_[c][i]), as_bf(x_[c][j]), acc0[i][j], 0, 0, 0);
          acc1[i][j] = __builtin_amdgcn_mfma_f32_16x16x32_bf16(as_bf(a_[c][i]), as_bf(y_[c][j]), acc1[i][j], 0, 0, 0);
        }
    }
    #pragma unroll
    for (int c = 0; c < 2; ++c)
      #pragma unroll
      for (int u = 0; u < 2; ++u) {
        a_[c][u] = an[c][u];
        x_[c][u] = xn[c][u];
        y_[c][u] = yn[c][u];
      }
  }

  #pragma unroll
  for (int i = 0; i < 2; ++i) {
    #pragma unroll
    for (int j = 0; j < 2; ++j) {
      int n = n0 + wn + j*16 + c16;
      if (n >= N) continue;
      float bv0 = bias0[n], bv1 = bias1[n];
      int mb = m0 + wm + i*16 + q4*4;
      #pragma unroll
      for (int r = 0; r < 4; ++r) {
        int m = mb + r;
        if (m >= M) continue;
        float z5 = acc0[i][j][r] + bv0;
        float z6 = acc1[i][j][r] + bv1;
        float v = z6 / (1.f + expf(-z5));
        if (sub) v -= b2f(sub[(ll)m*ldsub + n]);
        C[(ll)m*ldc + n] = f2b(v);
      }
    }
  }
}

// ------------------------------------------------------------------
extern "C" void kernel_launch(void* const* d_in, const int* in_sizes, int n_in,
                              void* d_out, int out_size, void* d_ws, size_t ws_size,
                              hipStream_t stream)
{
  (void)in_sizes; (void)n_in; (void)out_size; (void)ws_size;
  const float* x    = (const float*)d_in[0];
  const float* xm   = (const float*)d_in[1];
  const float* embw = (const float*)d_in[4];
  const float* embb = (const float*)d_in[5];
  const float* Wqf  = (const float*)d_in[6];
  const float* Wkf  = (const float*)d_in[7];
  const float* Wvf  = (const float*)d_in[8];
  const float* Wof  = (const float*)d_in[9];
  const float* W3f  = (const float*)d_in[10];
  const float* W4f  = (const float*)d_in[11];
  const float* bq   = (const float*)d_in[12];
  const float* bk   = (const float*)d_in[13];
  const float* bv   = (const float*)d_in[14];
  const float* bo   = (const float*)d_in[15];
  const float* b3   = (const float*)d_in[16];
  const float* b4   = (const float*)d_in[17];
  const float* W1f  = (const float*)d_in[18];
  const float* b1   = (const float*)d_in[19];
  const float* W2f  = (const float*)d_in[20];
  const float* b2   = (const float*)d_in[21];
  const float* W5f  = (const float*)d_in[22];
  const float* b5   = (const float*)d_in[23];
  const float* W6f  = (const float*)d_in[24];
  const float* b6   = (const float*)d_in[25];
  const float* ln1g = (const float*)d_in[26];
  const float* ln1b = (const float*)d_in[27];
  const float* ln2g = (const float*)d_in[28];
  const float* ln2b = (const float*)d_in[29];

  u8* ws = (u8*)d_ws;
  size_t off = 0;
  auto alloc = [&](size_t bytes) -> void* {
    void* ptr = ws + off;
    off = (off + bytes + 255) & ~(size_t)255;
    return ptr;
  };
  float* meanp = (float*)alloc((size_t)G16*ENC*4);
  float* stdp  = (float*)alloc((size_t)G16*ENC*4);
  float* partp = (float*)alloc((size_t)G16*TCH*1024*2*4);
  u16* xin   = (u16*)alloc((size_t)G16*NTOK*KPAD*2);
  u16* wp    = (u16*)alloc((size_t)DM*KPAD*2);
  const int nWsm = 2*DM*DM;
  const int nWff = 2*512*DM;
  const int nW56 = 2*SEQ*512;
  u16* Wqkv = (u16*)alloc((size_t)2*768*256*2);
  u16* Wo = (u16*)alloc((size_t)nWsm*2);
  u16* W3 = (u16*)alloc((size_t)nWsm*2);
  u16* W4 = (u16*)alloc((size_t)nWsm*2);
  u16* W1 = (u16*)alloc((size_t)nWff*2);
  u16* W2 = (u16*)alloc((size_t)nWff*2);
  u16* W5 = (u16*)alloc((size_t)nW56*2);
  u16* W6 = (u16*)alloc((size_t)nW56*2);
  float* bqkv = (float*)alloc((size_t)2*768*4);
  u16* hb    = (u16*)alloc((size_t)MTOT*DM*2);
  u16* qkvb  = (u16*)alloc((size_t)MTOT*768*2);
  u16* vT    = (u16*)alloc((size_t)G16*DM*SPAD*2);
  u16* attb  = (u16*)alloc((size_t)MTOT*DM*2);
  u16* catb  = (u16*)alloc((size_t)MTOT*512*2);
  u16* xlnb  = (u16*)alloc((size_t)MTOT*DM*2);
  u16* t1b   = (u16*)alloc((size_t)MTOT*512*2);
  u16* xsb   = (u16*)alloc((size_t)MTOT*DM*2);
  u16* hhb   = (u16*)alloc((size_t)MTOT*DM*2);
  u16* out0b = (u16*)alloc((size_t)MTOT*SEQ*2);
  u16* outFb = (u16*)alloc((size_t)MTOT*SEQ*2);

  // pipelined 64x64 single-B gemm
  auto gemm64_1 = [&](const u16* A, int lda, const u16* B, int ldb, const float* bias,
                      u16* C, int ldc, int M, int N, int K, int mode,
                      const u16* a1, int ld1, u16* a2, int ld2) {
    dim3 grid((N + 63) / 64, (M + 63) / 64, 1);
    gemm64<1><<<grid, 256, 0, stream>>>(A, B, nullptr, bias, nullptr, C, a1, a2, nullptr,
                                        M, N, K, lda, ldb, ldc, ld1, ld2, 0, mode);
  };
  // pipelined 64x64 dual-B gemm (glu) -- W3/W4 (N=256)
  auto gemm64_2 = [&](const u16* A, int lda, const u16* B0p, const u16* B1p, int ldb,
                      const float* bias0, const float* bias1, u16* C, int ldc,
                      const u16* sub, int ldsub, int M, int N, int K) {
    dim3 grid((N + 63) / 64, (M + 63) / 64, 1);
    gemm64<2><<<grid, 256, 0, stream>>>(A, B0p, B1p, bias0, bias1, C, nullptr, nullptr, sub,
                                        M, N, K, lda, ldb, ldc, 0, 0, ldsub, 0);
  };
  // register-tile dual-B gemm (no LDS / no barriers) -- W5/W6 (N=720, K=512)
  auto gemmDreg = [&](const u16* A, int lda, const u16* B0p, const u16* B1p, int ldb,
                      const float* bias0, const float* bias1, u16* C, int ldc,
                      const u16* sub, int ldsub, int M, int N, int K) {
    dim3 grid((N + 63) / 64, (M + 63) / 64, 1);
    gemm_reg_dual<<<grid, 256, 0, stream>>>(A, B0p, B1p, bias0, bias1, C, sub,
                                            M, N, K, lda, ldb, ldc, ldsub);
  };

  // weight conversion: one launch, 10 jobs
  CvtJobs J{};
  int nj = 0;
  auto addjob = [&](const float* s, u16* d, int n, int per, ll stride) {
    J.src[nj] = s; J.dst[nj] = d; J.n[nj] = n; J.per[nj] = per; J.stride[nj] = stride; nj++;
  };
  addjob(Wqf, Wqkv,           nWsm, 65536, 196608);
  addjob(Wkf, Wqkv + 65536,   nWsm, 65536, 196608);
  addjob(Wvf, Wqkv + 131072,  nWsm, 65536, 196608);
  addjob(Wof, Wo, nWsm, 0, 0);
  addjob(W3f, W3, nWsm, 0, 0);
  addjob(W4f, W4, nWsm, 0, 0);
  addjob(W1f, W1, nWff, 0, 0);
  addjob(W2f, W2, nWff, 0, 0);
  addjob(W5f, W5, nW56, 0, 0);
  addjob(W6f, W6, nW56, 0, 0);
  cvt_multi<<<dim3(512, 10), 256, 0, stream>>>(J);
  pack_bqkv<<<6, 256, 0, stream>>>(bq, bk, bv, bqkv);

  stats_part<<<dim3(4, TCH, 16), 256, 0, stream>>>(x, (float2*)partp);
  stats_reduce<<<64, 256, 0, stream>>>((const float2*)partp, meanp, stdp);
  build_xin<<<dim3(28, 24, 16), 256, 0, stream>>>(x, xm, meanp, stdp, xin);
  pack_embedw<<<256, 256, 0, stream>>>(embw, wp);

  // h = xin @ embed_w^T + embed_b
  gemm64_1(xin, KPAD, wp, KPAD, embb, hb, DM, MTOT, DM, KPAD, 0, nullptr, 0, nullptr, 0);

  for (int l = 0; l < 2; ++l) {
    const ll wOff = (ll)l * DM * DM;
    // fused qkv (q pre-scaled by scale*log2e)
    gemm64_1(hb, DM, Wqkv + (ll)l*768*256, 256, bqkv + l*768, qkvb, 768,
             MTOT, 768, DM, 5, nullptr, 0, nullptr, 0);
    transpose_v<<<dim3(8, 28, 16), 256, 0, stream>>>(qkvb + 512, 768, vT);

    flash_attn<<<dim3(7, 128), 256, 0, stream>>>(qkvb, qkvb + 256, 768, vT, attb);

    // x_att -> cat[:, 0:256]
    gemm64_1(attb, DM, Wo + wOff, DM, bo + l*DM, catb, 512, MTOT, DM, DM, 0, nullptr, 0, nullptr, 0);
    // x_ln = LN(h - x_att)
    ln_rows<<<MTOT/4, 256, 0, stream>>>(hb, catb, DM, 512, ln1g + l*DM, ln1b + l*DM, xlnb, DM, MTOT);
    // t1 = gelu(x_ln @ W1^T + b1)
    gemm64_1(xlnb, DM, W1 + (ll)l*512*DM, DM, b1 + l*512, t1b, 512, MTOT, 512, DM, 1, nullptr, 0, nullptr, 0);
    // y -> cat[:, 256:512]; xs = x_ln - y
    gemm64_1(t1b, 512, W2 + (ll)l*DM*512, 512, b2 + l*DM, catb + 256, 512, MTOT, DM, 512, 2, xlnb, DM, xsb, DM);
    // hh = sigmoid(xs W3^T + b3) * (xs W4^T + b4)
    gemm64_2(xsb, DM, W3 + wOff, W4 + wOff, DM, b3 + l*DM, b4 + l*DM, hhb, DM,
             nullptr, 0, MTOT, DM, DM);
    // h = LN(hh)
    ln_rows<<<MTOT/4, 256, 0, stream>>>(hhb, nullptr, DM, 0, ln2g + l*DM, ln2b + l*DM, hb, DM, MTOT);
    // out = sigmoid(cat W5^T + b5) * (cat W6^T + b6)  [- out0 on layer 1]
    if (l == 0)
      gemmDreg(catb, 512, W5 + (ll)l*SEQ*512, W6 + (ll)l*SEQ*512, 512,
               b5 + l*SEQ, b6 + l*SEQ, out0b, SEQ, nullptr, 0, MTOT, SEQ, 512);
    else
      gemmDreg(catb, 512, W5 + (ll)l*SEQ*512, W6 + (ll)l*SEQ*512, 512,
               b5 + l*SEQ, b6 + l*SEQ, outFb, SEQ, out0b, SEQ, MTOT, SEQ, 512);
  }

  final_combine<<<dim3(27, 23, 8), 256, 0, stream>>>(outFb, meanp, stdp, (float*)d_out);
}

// Round 8
// 640.931 us; speedup vs baseline: 1.1848x; 1.1848x over previous
//
#include <hip/hip_runtime.h>
#include <cstdint>
#include <cstddef>

#define DEV __device__ __forceinline__
#define AS1 __attribute__((address_space(1)))
#define AS3 __attribute__((address_space(3)))

typedef unsigned short u16;
typedef unsigned char u8;
typedef long long ll;

typedef __attribute__((ext_vector_type(8))) __bf16 bf16x8;
typedef __attribute__((ext_vector_type(8))) unsigned short u16x8;
typedef __attribute__((ext_vector_type(4))) float f32x4;

static constexpr int SEQ  = 720;
static constexpr int ENC  = 862;
static constexpr int NTOK = 866;            // ENC + MARK
static constexpr int DM   = 256;
static constexpr int G16  = 16;             // B * T_SCALES
static constexpr int MTOT = G16 * NTOK;     // 13856
static constexpr int KPAD = 768;            // SEQ padded to multiple of 64
static constexpr int SPAD = 896;            // 866 keys padded to multiple of 32
static constexpr int TCH  = 15;             // time chunks for stats (720 = 15*48)
static constexpr float SC2 = 0.17677669529663689f * 1.4426950408889634f; // scale*log2e

DEV float b2f(u16 v){ union { unsigned u; float f; } x; x.u = ((unsigned)v) << 16; return x.f; }
DEV u16 f2b(float f){ union { float f; unsigned u; } x; x.f = f;
  unsigned r = x.u + 0x7fffu + ((x.u >> 16) & 1u); return (u16)(r >> 16); }
DEV bf16x8 as_bf(u16x8 v){ return __builtin_bit_cast(bf16x8, v); }

// async global->LDS, 16B per lane; LDS base wave-uniform
DEV void g2l(const u16* g, u16* l){
  __builtin_amdgcn_global_load_lds((AS1 void*)g, (AS3 void*)l, 16, 0, 0);
}

// XCD-aware remap: XCD (L%8) owns a contiguous band of work-items
DEV int xcd_work(){
  int L = blockIdx.y * gridDim.x + blockIdx.x;
  int T = gridDim.x * gridDim.y;
  int x = L & 7, k = L >> 3;
  int q = T >> 3, r = T & 7;
  int mn = x < r ? x : r;
  return x*q + mn + k;
}

// ------------------------------------------------------------------
struct CvtJobs {
  const float* src[10];
  u16* dst[10];
  int n[10];
  int per[10];
  ll stride[10];
};
__global__ __launch_bounds__(256) void cvt_multi(CvtJobs J)
{
  int j = blockIdx.y;
  const float* s = J.src[j];
  u16* d = J.dst[j];
  int n = J.n[j], per = J.per[j];
  ll st = J.stride[j];
  for (int i = blockIdx.x*256 + threadIdx.x; i < n; i += gridDim.x*256) {
    ll di = per ? ((ll)(i/per)*st + (i%per)) : (ll)i;
    d[di] = f2b(s[i]);
  }
}

__global__ __launch_bounds__(256) void pack_bqkv(const float* __restrict__ bq,
                                                 const float* __restrict__ bk,
                                                 const float* __restrict__ bv,
                                                 float* __restrict__ out)
{
  int idx = blockIdx.x*256 + threadIdx.x;
  if (idx >= 1536) return;
  int l = idx / 768, j = idx % 768;
  float v;
  if (j < 256)      v = bq[l*256 + j];
  else if (j < 512) v = bk[l*256 + j - 256];
  else              v = bv[l*256 + j - 512];
  out[idx] = v;
}

// ------------------------------------------------------------------
// per-(group, column) mean/std over SEQ, two-pass deterministic.
// ------------------------------------------------------------------
__global__ __launch_bounds__(256) void stats_part(const float* __restrict__ x,
                                                  float2* __restrict__ part)
{
  int g  = blockIdx.z;
  int tc = blockIdx.y;
  int c  = (blockIdx.x << 8) + threadIdx.x;
  float s = 0.f, q = 0.f;
  if (c < ENC) {
    const float* xp = x + ((ll)g * SEQ + tc * 48) * ENC + c;
    #pragma unroll 8
    for (int t = 0; t < 48; ++t) {
      float v = xp[(ll)t * ENC];
      s += v; q += v * v;
    }
  }
  part[(((ll)g * TCH + tc) * 4 + blockIdx.x) * 256 + threadIdx.x] = make_float2(s, q);
}

__global__ __launch_bounds__(256) void stats_reduce(const float2* __restrict__ part,
                                                    float* __restrict__ meanp,
                                                    float* __restrict__ stdp)
{
  int g  = blockIdx.x >> 2;
  int cc = blockIdx.x & 3;
  int c  = (cc << 8) + threadIdx.x;
  if (c >= ENC) return;
  float s = 0.f, q = 0.f;
  #pragma unroll
  for (int t = 0; t < TCH; ++t) {
    float2 p = part[(((ll)g * TCH + t) * 4 + cc) * 256 + threadIdx.x];
    s += p.x; q += p.y;
  }
  float mn  = s * (1.f / SEQ);
  float var = q * (1.f / SEQ) - mn * mn;
  var = var < 0.f ? 0.f : var;
  meanp[g * ENC + c] = mn;
  stdp [g * ENC + c] = sqrtf(var + 1e-5f);
}

// ------------------------------------------------------------------
__global__ __launch_bounds__(256) void build_xin(const float* __restrict__ x,
                                                 const float* __restrict__ xm,
                                                 const float* __restrict__ meanp,
                                                 const float* __restrict__ stdp,
                                                 u16* __restrict__ xin)
{
  int g  = blockIdx.z;
  int c0 = blockIdx.x << 5, s0 = blockIdx.y << 5;
  __shared__ float tl[32][33];
  __shared__ float mn[32], isd[32];
  int tid = threadIdx.x;
  if (tid < 32) {
    int c = c0 + tid;
    float m = 0.f, s = 1.f;
    if (c < ENC) { m = meanp[g*ENC + c]; s = stdp[g*ENC + c]; }
    mn[tid] = m; isd[tid] = 1.f / s;
  }
  __syncthreads();
  int ci = tid & 31, r = tid >> 5;
  #pragma unroll
  for (int p = 0; p < 4; ++p) {
    int sl = r + (p << 3);
    int s = s0 + sl, c = c0 + ci;
    float v = 0.f;
    if (s < SEQ && c < NTOK) {
      if (c < ENC) v = (x[((ll)g*SEQ + s)*ENC + c] - mn[ci]) * isd[ci];
      else         v = xm[((ll)g*SEQ + s)*4 + (c - ENC)];
    }
    tl[sl][ci] = v;
  }
  __syncthreads();
  int si = tid & 31;
  #pragma unroll
  for (int p = 0; p < 4; ++p) {
    int cl = r + (p << 3);
    int c = c0 + cl;
    if (c < NTOK) xin[((ll)g*NTOK + c)*KPAD + s0 + si] = f2b(tl[si][cl]);
  }
}

// ------------------------------------------------------------------
__global__ __launch_bounds__(256) void pack_embedw(const float* __restrict__ ew,
                                                   u16* __restrict__ wp)
{
  int row = blockIdx.x;
  for (int c = threadIdx.x; c < KPAD; c += 256)
    wp[row*KPAD + c] = (c < SEQ) ? f2b(ew[row*SEQ + c]) : (u16)0;
}

// ------------------------------------------------------------------
__global__ __launch_bounds__(256) void transpose_v(const u16* __restrict__ v, int ldv,
                                                   u16* __restrict__ vT)
{
  int g = blockIdx.z;
  int d0 = blockIdx.x << 5, s0 = blockIdx.y << 5;
  __shared__ u16 tl[32][33];
  int tid = threadIdx.x;
  int di = tid & 31, r = tid >> 5;
  #pragma unroll
  for (int p = 0; p < 4; ++p) {
    int sl = r + (p << 3);
    int s = s0 + sl;
    u16 val = 0;
    if (s < NTOK) val = v[((ll)g*NTOK + s)*ldv + d0 + di];
    tl[sl][di] = val;
  }
  __syncthreads();
  int si = tid & 31;
  #pragma unroll
  for (int p = 0; p < 4; ++p) {
    int dl = r + (p << 3);
    vT[((ll)g*DM + d0 + dl)*SPAD + s0 + si] = tl[si][dl];
  }
}

// ------------------------------------------------------------------
// flash attention, fixed-max softmax (Q pre-scaled by scale*log2e).
// ------------------------------------------------------------------
__global__ __launch_bounds__(256) void flash_attn(const u16* __restrict__ qb,
                                                  const u16* __restrict__ kb,
                                                  int ldqk,
                                                  const u16* __restrict__ vT,
                                                  u16* __restrict__ attb)
{
  const int w = xcd_work();
  const int gh = w / 7;
  const int g = gh >> 3, h = gh & 7;
  const int q0 = (w % 7) * 128;
  const int tid = threadIdx.x, wv = tid >> 6, lane = tid & 63;
  const int q4 = lane >> 4, c16 = lane & 15;
  constexpr int PLD = 136;

  __shared__ __attribute__((aligned(16))) u16 Qs[128*32];
  __shared__ __attribute__((aligned(16))) u16 Ks[128*32];
  __shared__ __attribute__((aligned(16))) u16 Vs[32*PLD];
  __shared__ __attribute__((aligned(16))) u16 Ps[4][32*PLD];

  {
    int r = tid >> 1, sg = (tid & 1) << 4;
    int row = q0 + r; if (row > NTOK-1) row = NTOK-1;
    const u16* src = qb + ((ll)(g*NTOK + row))*ldqk + h*32 + sg;
    *(uint4*)&Qs[r*32 + sg]     = *(const uint4*)src;
    *(uint4*)&Qs[r*32 + sg + 8] = *(const uint4*)(src + 8);
  }
  __syncthreads();

  bf16x8 qf[2];
  qf[0] = as_bf(*(const u16x8*)&Qs[(wv*32 +      c16)*32 + q4*8]);
  qf[1] = as_bf(*(const u16x8*)&Qs[(wv*32 + 16 + c16)*32 + q4*8]);

  float lsum[2][4] = {{0,0,0,0},{0,0,0,0}};
  f32x4 oacc[2][2];
  oacc[0][0] = (f32x4){0,0,0,0}; oacc[0][1] = (f32x4){0,0,0,0};
  oacc[1][0] = (f32x4){0,0,0,0}; oacc[1][1] = (f32x4){0,0,0,0};

  for (int kt = 0; kt < 7; ++kt) {
    const int k0 = kt * 128;
    if (kt) __syncthreads();
    {
      int r = tid >> 1, sg = (tid & 1) << 4;
      int row = k0 + r; if (row > NTOK-1) row = NTOK-1;
      const u16* src = kb + ((ll)(g*NTOK + row))*ldqk + h*32 + sg;
      *(uint4*)&Ks[r*32 + sg]     = *(const uint4*)src;
      *(uint4*)&Ks[r*32 + sg + 8] = *(const uint4*)(src + 8);
    }
    {
      int e = tid >> 3, sg = (tid & 7) << 4;
      const u16* src = vT + ((ll)(g*DM + h*32 + e))*SPAD + k0 + sg;
      *(uint4*)&Vs[e*PLD + sg]     = *(const uint4*)src;
      *(uint4*)&Vs[e*PLD + sg + 8] = *(const uint4*)(src + 8);
    }
    __syncthreads();

    f32x4 s[2][8];
    #pragma unroll
    for (int i = 0; i < 2; ++i)
      #pragma unroll
      for (int j = 0; j < 8; ++j) s[i][j] = (f32x4){0,0,0,0};
    #pragma unroll
    for (int j = 0; j < 8; ++j) {
      bf16x8 kf = as_bf(*(const u16x8*)&Ks[(j*16 + c16)*32 + q4*8]);
      s[0][j] = __builtin_amdgcn_mfma_f32_16x16x32_bf16(qf[0], kf, s[0][j], 0, 0, 0);
      s[1][j] = __builtin_amdgcn_mfma_f32_16x16x32_bf16(qf[1], kf, s[1][j], 0, 0, 0);
    }
    if (kt == 6) {
      #pragma unroll
      for (int j = 0; j < 8; ++j) {
        if (k0 + j*16 + c16 >= NTOK) {
          #pragma unroll
          for (int r = 0; r < 4; ++r) { s[0][j][r] = -1e30f; s[1][j][r] = -1e30f; }
        }
      }
    }

    #pragma unroll
    for (int i = 0; i < 2; ++i)
      #pragma unroll
      for (int j = 0; j < 8; ++j)
        #pragma unroll
        for (int r = 0; r < 4; ++r) {
          float p = exp2f(s[i][j][r]);
          lsum[i][r] += p;
          unsigned u = __builtin_bit_cast(unsigned, p);
          Ps[wv][(i*16 + q4*4 + r)*PLD + j*16 + c16] = (u16)(u >> 16);
        }

    #pragma unroll
    for (int kk = 0; kk < 4; ++kk) {
      bf16x8 af0 = as_bf(*(const u16x8*)&Ps[wv][(     c16)*PLD + kk*32 + q4*8]);
      bf16x8 af1 = as_bf(*(const u16x8*)&Ps[wv][(16 + c16)*PLD + kk*32 + q4*8]);
      bf16x8 b0  = as_bf(*(const u16x8*)&Vs[(     c16)*PLD + kk*32 + q4*8]);
      bf16x8 b1  = as_bf(*(const u16x8*)&Vs[(16 + c16)*PLD + kk*32 + q4*8]);
      oacc[0][0] = __builtin_amdgcn_mfma_f32_16x16x32_bf16(af0, b0, oacc[0][0], 0, 0, 0);
      oacc[0][1] = __builtin_amdgcn_mfma_f32_16x16x32_bf16(af0, b1, oacc[0][1], 0, 0, 0);
      oacc[1][0] = __builtin_amdgcn_mfma_f32_16x16x32_bf16(af1, b0, oacc[1][0], 0, 0, 0);
      oacc[1][1] = __builtin_amdgcn_mfma_f32_16x16x32_bf16(af1, b1, oacc[1][1], 0, 0, 0);
    }
  }

  float linv[2][4];
  #pragma unroll
  for (int i = 0; i < 2; ++i)
    #pragma unroll
    for (int r = 0; r < 4; ++r) {
      float t = lsum[i][r];
      t += __shfl_xor(t, 1, 64);
      t += __shfl_xor(t, 2, 64);
      t += __shfl_xor(t, 4, 64);
      t += __shfl_xor(t, 8, 64);
      linv[i][r] = 1.f / t;
    }
  #pragma unroll
  for (int i = 0; i < 2; ++i)
    #pragma unroll
    for (int jn = 0; jn < 2; ++jn)
      #pragma unroll
      for (int r = 0; r < 4; ++r) {
        int row = q0 + wv*32 + i*16 + q4*4 + r;
        if (row < NTOK)
          attb[((ll)(g*NTOK + row))*DM + h*32 + jn*16 + c16] =
            f2b(oacc[i][jn][r] * linv[i][r]);
      }
}

// ------------------------------------------------------------------
__global__ __launch_bounds__(256) void ln_rows(const u16* __restrict__ in1,
                                               const u16* __restrict__ in2,
                                               int ld1, int ld2,
                                               const float* __restrict__ gamma,
                                               const float* __restrict__ beta,
                                               u16* __restrict__ out, int ldo, int Mrows)
{
  int row = blockIdx.x*4 + (threadIdx.x >> 6);
  int lane = threadIdx.x & 63;
  if (row >= Mrows) return;
  float xv[4];
  ushort4 a = *(const ushort4*)(in1 + (ll)row*ld1 + lane*4);
  xv[0]=b2f(a.x); xv[1]=b2f(a.y); xv[2]=b2f(a.z); xv[3]=b2f(a.w);
  if (in2) {
    ushort4 b = *(const ushort4*)(in2 + (ll)row*ld2 + lane*4);
    xv[0]-=b2f(b.x); xv[1]-=b2f(b.y); xv[2]-=b2f(b.z); xv[3]-=b2f(b.w);
  }
  float s = xv[0]+xv[1]+xv[2]+xv[3];
  #pragma unroll
  for (int o = 32; o > 0; o >>= 1) s += __shfl_xor(s, o, 64);
  float mean = s * (1.f/256.f);
  float d0=xv[0]-mean, d1=xv[1]-mean, d2=xv[2]-mean, d3=xv[3]-mean;
  float q = d0*d0 + d1*d1 + d2*d2 + d3*d3;
  #pragma unroll
  for (int o = 32; o > 0; o >>= 1) q += __shfl_xor(q, o, 64);
  float rstd = 1.f / sqrtf(q * (1.f/256.f) + 1e-5f);
  float4 gv = *(const float4*)(gamma + lane*4);
  float4 bb = *(const float4*)(beta  + lane*4);
  ushort4 o4;
  o4.x = f2b(d0*rstd*gv.x + bb.x);
  o4.y = f2b(d1*rstd*gv.y + bb.y);
  o4.z = f2b(d2*rstd*gv.z + bb.z);
  o4.w = f2b(d3*rstd*gv.w + bb.w);
  *(ushort4*)(out + (ll)row*ldo + lane*4) = o4;
}

// ------------------------------------------------------------------
__global__ __launch_bounds__(256) void final_combine(const u16* __restrict__ outF,
                                                     const float* __restrict__ meanp,
                                                     const float* __restrict__ stdp,
                                                     float* __restrict__ dout)
{
  int b = blockIdx.z;
  int c0 = blockIdx.x << 5, s0 = blockIdx.y << 5;
  __shared__ float tl[32][33];
  int tid = threadIdx.x;
  int si = tid & 31, r = tid >> 5;
  #pragma unroll
  for (int p = 0; p < 4; ++p) {
    int cl = r + (p << 3);
    int c = c0 + cl, s = s0 + si;
    float accv = 0.f;
    #pragma unroll
    for (int t = 0; t < 2; ++t) {
      int g = b*2 + t;
      if (c < ENC && s < SEQ) {
        float v = b2f(outF[((ll)(g*NTOK + c))*SEQ + s]);
        accv += 0.5f * (v * stdp[g*ENC + c] + meanp[g*ENC + c]);
      }
    }
    tl[cl][si] = accv;
  }
  __syncthreads();
  int ci = tid & 31;
  #pragma unroll
  for (int p = 0; p < 4; ++p) {
    int sl = r + (p << 3);
    int s = s0 + sl, c = c0 + ci;
    if (s < SEQ && c < ENC)
      dout[((ll)b*SEQ + s)*ENC + c] = tl[ci][sl];
  }
}

// ------------------------------------------------------------------
// Pipelined 64x64-tile NT GEMM, K-step 64 (two 32-wide panels),
// double-buffered LDS, raw s_barrier + counted vmcnt (T3/T4 recipe).
// Conflict-free XOR swizzle both sides (rule #21, verified r5: 0 conflicts).
// NB=1: modes 0 store / 1 gelu / 2 store+sub / 5 qkv. 32 KiB, 5 blk/CU.
// NB=2: 48 KiB, 3 blk/CU (used for W3/W4: N=256 keeps block count high).
// ------------------------------------------------------------------
template<int NB>
__global__ __launch_bounds__(256, NB == 1 ? 5 : 3) void gemm64(
    const u16* __restrict__ A, const u16* __restrict__ B0, const u16* __restrict__ B1,
    const float* __restrict__ bias0, const float* __restrict__ bias1,
    u16* __restrict__ C,
    const u16* __restrict__ aux1, u16* __restrict__ aux2, const u16* __restrict__ sub,
    int M, int N, int K, int lda, int ldb, int ldc, int ld1, int ld2, int ldsub, int mode)
{
  // [buf p][panel c] tiles of 64 rows x 32 cols, row-major ld=32
  __shared__ __attribute__((aligned(16))) u16 S[8192 * (1 + NB)];

  const int tid  = threadIdx.x;
  const int wv   = tid >> 6;
  const int lane = tid & 63;
  const int q4   = lane >> 4;
  const int c16  = lane & 15;

  const int w  = xcd_work();
  const int n0 = (w % gridDim.x) * 64;
  const int m0 = (w / gridDim.x) * 64;
  const int wm = (wv >> 1) * 32;
  const int wn = (wv & 1) * 32;

  // staging: 16 rows x 64 B per g2l; source chunk pre-swizzled so the
  // linear LDS write produces the XOR-swizzled layout
  const int lrow = lane >> 2;                                   // 0..15
  const int lcol = (((lane & 3) ^ ((lrow >> 1) & 3)) << 3);     // u16 offset

  int arow = m0 + wv*16 + lrow; if (arow >= M) arow = M-1;
  int brow = n0 + wv*16 + lrow; if (brow >= N) brow = N-1;
  const u16* pa  = A  + (ll)arow*lda + lcol;
  const u16* pb0 = B0 + (ll)brow*ldb + lcol;
  const u16* pb1 = (NB == 2) ? B1 + (ll)brow*ldb + lcol : nullptr;

  f32x4 acc0[2][2];
  f32x4 acc1[2][2];
  #pragma unroll
  for (int i = 0; i < 2; ++i)
    #pragma unroll
    for (int j = 0; j < 2; ++j) {
      acc0[i][j] = (f32x4){0,0,0,0};
      if constexpr (NB == 2) acc1[i][j] = (f32x4){0,0,0,0};
    }

  const int nk = K >> 6;
  auto issue = [&](int kt2, int p) {
    const int ko = kt2 * 64;
    #pragma unroll
    for (int c = 0; c < 2; ++c) {
      g2l(pa  + ko + c*32, &S[(p*2 + c)*2048 + (wv*16)*32]);
      g2l(pb0 + ko + c*32, &S[8192 + (p*2 + c)*2048 + (wv*16)*32]);
      if constexpr (NB == 2)
        g2l(pb1 + ko + c*32, &S[16384 + (p*2 + c)*2048 + (wv*16)*32]);
    }
  };

  issue(0, 0);
  for (int kt = 0; kt < nk; ++kt) {
    const int p = kt & 1;
    if (kt + 1 < nk) {
      issue(kt + 1, p ^ 1);
      // counted wait: just-issued loads (4 or 6) stay in flight
      if constexpr (NB == 1) asm volatile("s_waitcnt vmcnt(4)" ::: "memory");
      else                   asm volatile("s_waitcnt vmcnt(6)" ::: "memory");
    } else {
      asm volatile("s_waitcnt vmcnt(0)" ::: "memory");
    }
    __builtin_amdgcn_s_barrier();
    asm volatile("" ::: "memory");

    const int sw = ((q4 ^ ((c16 >> 1) & 3)) << 3);  // swizzled read chunk
    #pragma unroll
    for (int c = 0; c < 2; ++c) {
      const u16* as_ = &S[(p*2 + c)*2048];
      const u16* b0s = &S[8192 + (p*2 + c)*2048];
      bf16x8 af[2], bfv[2];
      #pragma unroll
      for (int i = 0; i < 2; ++i)
        af[i] = as_bf(*(const u16x8*)&as_[(wm + i*16 + c16)*32 + sw]);
      #pragma unroll
      for (int j = 0; j < 2; ++j)
        bfv[j] = as_bf(*(const u16x8*)&b0s[(wn + j*16 + c16)*32 + sw]);
      #pragma unroll
      for (int i = 0; i < 2; ++i)
        #pragma unroll
        for (int j = 0; j < 2; ++j)
          acc0[i][j] = __builtin_amdgcn_mfma_f32_16x16x32_bf16(af[i], bfv[j], acc0[i][j], 0, 0, 0);
      if constexpr (NB == 2) {
        const u16* b1s = &S[16384 + (p*2 + c)*2048];
        bf16x8 b1v[2];
        #pragma unroll
        for (int j = 0; j < 2; ++j)
          b1v[j] = as_bf(*(const u16x8*)&b1s[(wn + j*16 + c16)*32 + sw]);
        #pragma unroll
        for (int i = 0; i < 2; ++i)
          #pragma unroll
          for (int j = 0; j < 2; ++j)
            acc1[i][j] = __builtin_amdgcn_mfma_f32_16x16x32_bf16(af[i], b1v[j], acc1[i][j], 0, 0, 0);
      }
    }

    asm volatile("s_waitcnt lgkmcnt(0)" ::: "memory");
    __builtin_amdgcn_s_barrier();
  }

  #pragma unroll
  for (int i = 0; i < 2; ++i) {
    #pragma unroll
    for (int j = 0; j < 2; ++j) {
      int n = n0 + wn + j*16 + c16;
      if (n >= N) continue;
      float bv0 = bias0 ? bias0[n] : 0.f;
      float bv1 = (NB == 2) ? bias1[n] : 0.f;
      int mb = m0 + wm + i*16 + q4*4;
      #pragma unroll
      for (int r = 0; r < 4; ++r) {
        int m = mb + r;
        if (m >= M) continue;
        ll ci = (ll)m*ldc + n;
        if constexpr (NB == 2) {
          float z5 = acc0[i][j][r] + bv0;
          float z6 = acc1[i][j][r] + bv1;
          float v = z6 / (1.f + expf(-z5));
          if (sub) v -= b2f(sub[(ll)m*ldsub + n]);
          C[ci] = f2b(v);
        } else {
          float x = acc0[i][j][r] + bv0;
          if (mode == 0) {
            C[ci] = f2b(x);
          } else if (mode == 1) {
            C[ci] = f2b(0.5f * x * (1.f + erff(x * 0.70710678118654752f)));
          } else if (mode == 5) {
            C[ci] = f2b(n < 256 ? x * SC2 : x);
          } else { // mode 2
            C[ci] = f2b(x);
            float xl = b2f(aux1[(ll)m*ld1 + n]);
            aux2[(ll)m*ld2 + n] = f2b(xl - x);
          }
        }
      }
    }
  }
}

// ------------------------------------------------------------------
// 128x128-tile dual-B NT GEMM for W5/W6, BK=32, 4 waves each owning a
// 64x64 sub-tile of BOTH outputs.
// WHY (r2-r7 closed-form model): gemm64<2> is LDS-read-BW bound:
//   144 ds_read_b128/CU-step x 12cy = 1735cy -> 59us (meas 61);
//   MfmaUtil = 233/1735 = 13.4% (meas 13.4). FLOP/LDS-byte is set by
//   the WAVE tile: 32x32 -> 21.3, 64x32 -> 32, 64x64 -> 42.7 F/B.
//   This kernel: 12 reads feed 32 MFMA per wave-step (2x gemm64<2>).
// r7 proved the no-LDS register path is TA/L1-issue bound (134us) --
// LDS staging stays; schedule/swizzle carried unchanged from the
// race-proven gemm64 (issue; vmcnt(6); barrier; compute; lgkm0; barrier).
// LDS 48 KiB; VGPR ~190 (acc 128) -> 2 blk/CU. Grid 6x109 = 654 blocks.
// C = sig(A B0^T + b0) * (A B1^T + b1) [- sub].
// ------------------------------------------------------------------
__global__ __launch_bounds__(256, 2) void gemm_dual_w64(
    const u16* __restrict__ A, const u16* __restrict__ B0, const u16* __restrict__ B1,
    const float* __restrict__ bias0, const float* __restrict__ bias1,
    u16* __restrict__ C, const u16* __restrict__ sub,
    int M, int N, int K, int lda, int ldb, int ldc, int ldsub)
{
  // A: 2buf x 128x32 = 8192 u16; B0 @8192 same; B1 @16384 same. 48 KiB.
  __shared__ __attribute__((aligned(16))) u16 S[24576];

  const int tid  = threadIdx.x;
  const int wv   = tid >> 6;
  const int lane = tid & 63;
  const int q4   = lane >> 4;
  const int c16  = lane & 15;

  const int w  = xcd_work();
  const int n0 = (w % gridDim.x) * 128;
  const int m0 = (w / gridDim.x) * 128;
  const int wm = (wv >> 1) * 64;
  const int wn = (wv & 1) * 64;

  // staging: each wave stages rows [wv*32, wv*32+32) of A, B0, B1
  // (2 g2l each, 16 rows x 64 B); source pre-swizzled (rule #21)
  const int lrow = lane >> 2;                                   // 0..15
  const int lcol = (((lane & 3) ^ ((lrow >> 1) & 3)) << 3);     // u16 offset

  int ar0 = m0 + wv*32 + lrow;      if (ar0 >= M) ar0 = M-1;
  int ar1 = m0 + wv*32 + 16 + lrow; if (ar1 >= M) ar1 = M-1;
  int br0 = n0 + wv*32 + lrow;      if (br0 >= N) br0 = N-1;
  int br1 = n0 + wv*32 + 16 + lrow; if (br1 >= N) br1 = N-1;
  const u16* pa0  = A  + (ll)ar0*lda + lcol;
  const u16* pa1  = A  + (ll)ar1*lda + lcol;
  const u16* pb00 = B0 + (ll)br0*ldb + lcol;
  const u16* pb01 = B0 + (ll)br1*ldb + lcol;
  const u16* pb10 = B1 + (ll)br0*ldb + lcol;
  const u16* pb11 = B1 + (ll)br1*ldb + lcol;

  f32x4 acc0[4][4], acc1[4][4];   // 128 VGPR accumulator
  #pragma unroll
  for (int i = 0; i < 4; ++i)
    #pragma unroll
    for (int j = 0; j < 4; ++j) {
      acc0[i][j] = (f32x4){0,0,0,0};
      acc1[i][j] = (f32x4){0,0,0,0};
    }

  const int nk = K >> 5;          // BK=32
  auto issue = [&](int kt2, int p) {
    const int ko = kt2 * 32;
    g2l(pa0  + ko, &S[p*4096 + (wv*32)*32]);
    g2l(pa1  + ko, &S[p*4096 + (wv*32 + 16)*32]);
    g2l(pb00 + ko, &S[8192  + p*4096 + (wv*32)*32]);
    g2l(pb01 + ko, &S[8192  + p*4096 + (wv*32 + 16)*32]);
    g2l(pb10 + ko, &S[16384 + p*4096 + (wv*32)*32]);
    g2l(pb11 + ko, &S[16384 + p*4096 + (wv*32 + 16)*32]);
  };

  issue(0, 0);
  for (int kt = 0; kt < nk; ++kt) {
    const int p = kt & 1;
    if (kt + 1 < nk) {
      issue(kt + 1, p ^ 1);
      asm volatile("s_waitcnt vmcnt(6)" ::: "memory");  // 6 new stay in flight
    } else {
      asm volatile("s_waitcnt vmcnt(0)" ::: "memory");
    }
    __builtin_amdgcn_s_barrier();
    asm volatile("" ::: "memory");

    const int sw = ((q4 ^ ((c16 >> 1) & 3)) << 3);  // swizzled read chunk
    const u16* as_ = &S[p*4096];
    const u16* b0s = &S[8192  + p*4096];
    const u16* b1s = &S[16384 + p*4096];
    bf16x8 af[4], b0v[4], b1v[4];
    #pragma unroll
    for (int i = 0; i < 4; ++i)
      af[i] = as_bf(*(const u16x8*)&as_[(wm + i*16 + c16)*32 + sw]);
    #pragma unroll
    for (int j = 0; j < 4; ++j) {
      b0v[j] = as_bf(*(const u16x8*)&b0s[(wn + j*16 + c16)*32 + sw]);
      b1v[j] = as_bf(*(const u16x8*)&b1s[(wn + j*16 + c16)*32 + sw]);
    }
    #pragma unroll
    for (int i = 0; i < 4; ++i)
      #pragma unroll
      for (int j = 0; j < 4; ++j) {
        acc0[i][j] = __builtin_amdgcn_mfma_f32_16x16x32_bf16(af[i], b0v[j], acc0[i][j], 0, 0, 0);
        acc1[i][j] = __builtin_amdgcn_mfma_f32_16x16x32_bf16(af[i], b1v[j], acc1[i][j], 0, 0, 0);
      }

    asm volatile("s_waitcnt lgkmcnt(0)" ::: "memory");
    __builtin_amdgcn_s_barrier();
  }

  #pragma unroll
  for (int i = 0; i < 4; ++i) {
    #pragma unroll
    for (int j = 0; j < 4; ++j) {
      int n = n0 + wn + j*16 + c16;
      if (n >= N) continue;
      float bv0 = bias0[n], bv1 = bias1[n];
      int mb = m0 + wm + i*16 + q4*4;
      #pragma unroll
      for (int r = 0; r < 4; ++r) {
        int m = mb + r;
        if (m >= M) continue;
        float z5 = acc0[i][j][r] + bv0;
        float z6 = acc1[i][j][r] + bv1;
        float v = z6 / (1.f + expf(-z5));
        if (sub) v -= b2f(sub[(ll)m*ldsub + n]);
        C[(ll)m*ldc + n] = f2b(v);
      }
    }
  }
}

// ------------------------------------------------------------------
extern "C" void kernel_launch(void* const* d_in, const int* in_sizes, int n_in,
                              void* d_out, int out_size, void* d_ws, size_t ws_size,
                              hipStream_t stream)
{
  (void)in_sizes; (void)n_in; (void)out_size; (void)ws_size;
  const float* x    = (const float*)d_in[0];
  const float* xm   = (const float*)d_in[1];
  const float* embw = (const float*)d_in[4];
  const float* embb = (const float*)d_in[5];
  const float* Wqf  = (const float*)d_in[6];
  const float* Wkf  = (const float*)d_in[7];
  const float* Wvf  = (const float*)d_in[8];
  const float* Wof  = (const float*)d_in[9];
  const float* W3f  = (const float*)d_in[10];
  const float* W4f  = (const float*)d_in[11];
  const float* bq   = (const float*)d_in[12];
  const float* bk   = (const float*)d_in[13];
  const float* bv   = (const float*)d_in[14];
  const float* bo   = (const float*)d_in[15];
  const float* b3   = (const float*)d_in[16];
  const float* b4   = (const float*)d_in[17];
  const float* W1f  = (const float*)d_in[18];
  const float* b1   = (const float*)d_in[19];
  const float* W2f  = (const float*)d_in[20];
  const float* b2   = (const float*)d_in[21];
  const float* W5f  = (const float*)d_in[22];
  const float* b5   = (const float*)d_in[23];
  const float* W6f  = (const float*)d_in[24];
  const float* b6   = (const float*)d_in[25];
  const float* ln1g = (const float*)d_in[26];
  const float* ln1b = (const float*)d_in[27];
  const float* ln2g = (const float*)d_in[28];
  const float* ln2b = (const float*)d_in[29];

  u8* ws = (u8*)d_ws;
  size_t off = 0;
  auto alloc = [&](size_t bytes) -> void* {
    void* ptr = ws + off;
    off = (off + bytes + 255) & ~(size_t)255;
    return ptr;
  };
  float* meanp = (float*)alloc((size_t)G16*ENC*4);
  float* stdp  = (float*)alloc((size_t)G16*ENC*4);
  float* partp = (float*)alloc((size_t)G16*TCH*1024*2*4);
  u16* xin   = (u16*)alloc((size_t)G16*NTOK*KPAD*2);
  u16* wp    = (u16*)alloc((size_t)DM*KPAD*2);
  const int nWsm = 2*DM*DM;
  const int nWff = 2*512*DM;
  const int nW56 = 2*SEQ*512;
  u16* Wqkv = (u16*)alloc((size_t)2*768*256*2);
  u16* Wo = (u16*)alloc((size_t)nWsm*2);
  u16* W3 = (u16*)alloc((size_t)nWsm*2);
  u16* W4 = (u16*)alloc((size_t)nWsm*2);
  u16* W1 = (u16*)alloc((size_t)nWff*2);
  u16* W2 = (u16*)alloc((size_t)nWff*2);
  u16* W5 = (u16*)alloc((size_t)nW56*2);
  u16* W6 = (u16*)alloc((size_t)nW56*2);
  float* bqkv = (float*)alloc((size_t)2*768*4);
  u16* hb    = (u16*)alloc((size_t)MTOT*DM*2);
  u16* qkvb  = (u16*)alloc((size_t)MTOT*768*2);
  u16* vT    = (u16*)alloc((size_t)G16*DM*SPAD*2);
  u16* attb  = (u16*)alloc((size_t)MTOT*DM*2);
  u16* catb  = (u16*)alloc((size_t)MTOT*512*2);
  u16* xlnb  = (u16*)alloc((size_t)MTOT*DM*2);
  u16* t1b   = (u16*)alloc((size_t)MTOT*512*2);
  u16* xsb   = (u16*)alloc((size_t)MTOT*DM*2);
  u16* hhb   = (u16*)alloc((size_t)MTOT*DM*2);
  u16* out0b = (u16*)alloc((size_t)MTOT*SEQ*2);
  u16* outFb = (u16*)alloc((size_t)MTOT*SEQ*2);

  // pipelined 64x64 single-B gemm
  auto gemm64_1 = [&](const u16* A, int lda, const u16* B, int ldb, const float* bias,
                      u16* C, int ldc, int M, int N, int K, int mode,
                      const u16* a1, int ld1, u16* a2, int ld2) {
    dim3 grid((N + 63) / 64, (M + 63) / 64, 1);
    gemm64<1><<<grid, 256, 0, stream>>>(A, B, nullptr, bias, nullptr, C, a1, a2, nullptr,
                                        M, N, K, lda, ldb, ldc, ld1, ld2, 0, mode);
  };
  // pipelined 64x64 dual-B gemm (glu) -- W3/W4 (N=256)
  auto gemm64_2 = [&](const u16* A, int lda, const u16* B0p, const u16* B1p, int ldb,
                      const float* bias0, const float* bias1, u16* C, int ldc,
                      const u16* sub, int ldsub, int M, int N, int K) {
    dim3 grid((N + 63) / 64, (M + 63) / 64, 1);
    gemm64<2><<<grid, 256, 0, stream>>>(A, B0p, B1p, bias0, bias1, C, nullptr, nullptr, sub,
                                        M, N, K, lda, ldb, ldc, 0, 0, ldsub, 0);
  };
  // 128x128 dual-B gemm, 64x64 wave tiles -- W5/W6 (N=720, K=512)
  auto gemmDw64 = [&](const u16* A, int lda, const u16* B0p, const u16* B1p, int ldb,
                      const float* bias0, const float* bias1, u16* C, int ldc,
                      const u16* sub, int ldsub, int M, int N, int K) {
    dim3 grid((N + 127) / 128, (M + 127) / 128, 1);
    gemm_dual_w64<<<grid, 256, 0, stream>>>(A, B0p, B1p, bias0, bias1, C, sub,
                                            M, N, K, lda, ldb, ldc, ldsub);
  };

  // weight conversion: one launch, 10 jobs
  CvtJobs J{};
  int nj = 0;
  auto addjob = [&](const float* s, u16* d, int n, int per, ll stride) {
    J.src[nj] = s; J.dst[nj] = d; J.n[nj] = n; J.per[nj] = per; J.stride[nj] = stride; nj++;
  };
  addjob(Wqf, Wqkv,           nWsm, 65536, 196608);
  addjob(Wkf, Wqkv + 65536,   nWsm, 65536, 196608);
  addjob(Wvf, Wqkv + 131072,  nWsm, 65536, 196608);
  addjob(Wof, Wo, nWsm, 0, 0);
  addjob(W3f, W3, nWsm, 0, 0);
  addjob(W4f, W4, nWsm, 0, 0);
  addjob(W1f, W1, nWff, 0, 0);
  addjob(W2f, W2, nWff, 0, 0);
  addjob(W5f, W5, nW56, 0, 0);
  addjob(W6f, W6, nW56, 0, 0);
  cvt_multi<<<dim3(512, 10), 256, 0, stream>>>(J);
  pack_bqkv<<<6, 256, 0, stream>>>(bq, bk, bv, bqkv);

  stats_part<<<dim3(4, TCH, 16), 256, 0, stream>>>(x, (float2*)partp);
  stats_reduce<<<64, 256, 0, stream>>>((const float2*)partp, meanp, stdp);
  build_xin<<<dim3(28, 24, 16), 256, 0, stream>>>(x, xm, meanp, stdp, xin);
  pack_embedw<<<256, 256, 0, stream>>>(embw, wp);

  // h = xin @ embed_w^T + embed_b
  gemm64_1(xin, KPAD, wp, KPAD, embb, hb, DM, MTOT, DM, KPAD, 0, nullptr, 0, nullptr, 0);

  for (int l = 0; l < 2; ++l) {
    const ll wOff = (ll)l * DM * DM;
    // fused qkv (q pre-scaled by scale*log2e)
    gemm64_1(hb, DM, Wqkv + (ll)l*768*256, 256, bqkv + l*768, qkvb, 768,
             MTOT, 768, DM, 5, nullptr, 0, nullptr, 0);
    transpose_v<<<dim3(8, 28, 16), 256, 0, stream>>>(qkvb + 512, 768, vT);

    flash_attn<<<dim3(7, 128), 256, 0, stream>>>(qkvb, qkvb + 256, 768, vT, attb);

    // x_att -> cat[:, 0:256]
    gemm64_1(attb, DM, Wo + wOff, DM, bo + l*DM, catb, 512, MTOT, DM, DM, 0, nullptr, 0, nullptr, 0);
    // x_ln = LN(h - x_att)
    ln_rows<<<MTOT/4, 256, 0, stream>>>(hb, catb, DM, 512, ln1g + l*DM, ln1b + l*DM, xlnb, DM, MTOT);
    // t1 = gelu(x_ln @ W1^T + b1)
    gemm64_1(xlnb, DM, W1 + (ll)l*512*DM, DM, b1 + l*512, t1b, 512, MTOT, 512, DM, 1, nullptr, 0, nullptr, 0);
    // y -> cat[:, 256:512]; xs = x_ln - y
    gemm64_1(t1b, 512, W2 + (ll)l*DM*512, 512, b2 + l*DM, catb + 256, 512, MTOT, DM, 512, 2, xlnb, DM, xsb, DM);
    // hh = sigmoid(xs W3^T + b3) * (xs W4^T + b4)
    gemm64_2(xsb, DM, W3 + wOff, W4 + wOff, DM, b3 + l*DM, b4 + l*DM, hhb, DM,
             nullptr, 0, MTOT, DM, DM);
    // h = LN(hh)
    ln_rows<<<MTOT/4, 256, 0, stream>>>(hhb, nullptr, DM, 0, ln2g + l*DM, ln2b + l*DM, hb, DM, MTOT);
    // out = sigmoid(cat W5^T + b5) * (cat W6^T + b6)  [- out0 on layer 1]
    if (l == 0)
      gemmDw64(catb, 512, W5 + (ll)l*SEQ*512, W6 + (ll)l*SEQ*512, 512,
               b5 + l*SEQ, b6 + l*SEQ, out0b, SEQ, nullptr, 0, MTOT, SEQ, 512);
    else
      gemmDw64(catb, 512, W5 + (ll)l*SEQ*512, W6 + (ll)l*SEQ*512, 512,
               b5 + l*SEQ, b6 + l*SEQ, outFb, SEQ, out0b, SEQ, MTOT, SEQ, 512);
  }

  final_combine<<<dim3(27, 23, 8), 256, 0, stream>>>(outFb, meanp, stdp, (float*)d_out);
}

// Round 9
// 610.814 us; speedup vs baseline: 1.2433x; 1.0493x over previous
//
#include <hip/hip_runtime.h>
#include <cstdint>
#include <cstddef>

#define DEV __device__ __forceinline__
#define AS1 __attribute__((address_space(1)))
#define AS3 __attribute__((address_space(3)))

typedef unsigned short u16;
typedef unsigned char u8;
typedef long long ll;

typedef __attribute__((ext_vector_type(8))) __bf16 bf16x8;
typedef __attribute__((ext_vector_type(8))) unsigned short u16x8;
typedef __attribute__((ext_vector_type(4))) float f32x4;

static constexpr int SEQ  = 720;
static constexpr int ENC  = 862;
static constexpr int NTOK = 866;            // ENC + MARK
static constexpr int DM   = 256;
static constexpr int G16  = 16;             // B * T_SCALES
static constexpr int MTOT = G16 * NTOK;     // 13856
static constexpr int KPAD = 768;            // SEQ padded to multiple of 64
static constexpr int SPAD = 896;            // 866 keys padded to multiple of 32
static constexpr int TCH  = 15;             // time chunks for stats (720 = 15*48)
static constexpr float SC2 = 0.17677669529663689f * 1.4426950408889634f; // scale*log2e

DEV float b2f(u16 v){ union { unsigned u; float f; } x; x.u = ((unsigned)v) << 16; return x.f; }
DEV u16 f2b(float f){ union { float f; unsigned u; } x; x.f = f;
  unsigned r = x.u + 0x7fffu + ((x.u >> 16) & 1u); return (u16)(r >> 16); }
DEV bf16x8 as_bf(u16x8 v){ return __builtin_bit_cast(bf16x8, v); }

// async global->LDS, 16B per lane; LDS base wave-uniform
DEV void g2l(const u16* g, u16* l){
  __builtin_amdgcn_global_load_lds((AS1 void*)g, (AS3 void*)l, 16, 0, 0);
}

// XCD-aware remap: XCD (L%8) owns a contiguous band of work-items
DEV int xcd_work(){
  int L = blockIdx.y * gridDim.x + blockIdx.x;
  int T = gridDim.x * gridDim.y;
  int x = L & 7, k = L >> 3;
  int q = T >> 3, r = T & 7;
  int mn = x < r ? x : r;
  return x*q + mn + k;
}

// ------------------------------------------------------------------
struct CvtJobs {
  const float* src[10];
  u16* dst[10];
  int n[10];
  int per[10];
  ll stride[10];
};
__global__ __launch_bounds__(256) void cvt_multi(CvtJobs J)
{
  int j = blockIdx.y;
  const float* s = J.src[j];
  u16* d = J.dst[j];
  int n = J.n[j], per = J.per[j];
  ll st = J.stride[j];
  for (int i = blockIdx.x*256 + threadIdx.x; i < n; i += gridDim.x*256) {
    ll di = per ? ((ll)(i/per)*st + (i%per)) : (ll)i;
    d[di] = f2b(s[i]);
  }
}

__global__ __launch_bounds__(256) void pack_bqkv(const float* __restrict__ bq,
                                                 const float* __restrict__ bk,
                                                 const float* __restrict__ bv,
                                                 float* __restrict__ out)
{
  int idx = blockIdx.x*256 + threadIdx.x;
  if (idx >= 1536) return;
  int l = idx / 768, j = idx % 768;
  float v;
  if (j < 256)      v = bq[l*256 + j];
  else if (j < 512) v = bk[l*256 + j - 256];
  else              v = bv[l*256 + j - 512];
  out[idx] = v;
}

// ------------------------------------------------------------------
// per-(group, column) mean/std over SEQ, two-pass deterministic.
// ------------------------------------------------------------------
__global__ __launch_bounds__(256) void stats_part(const float* __restrict__ x,
                                                  float2* __restrict__ part)
{
  int g  = blockIdx.z;
  int tc = blockIdx.y;
  int c  = (blockIdx.x << 8) + threadIdx.x;
  float s = 0.f, q = 0.f;
  if (c < ENC) {
    const float* xp = x + ((ll)g * SEQ + tc * 48) * ENC + c;
    #pragma unroll 8
    for (int t = 0; t < 48; ++t) {
      float v = xp[(ll)t * ENC];
      s += v; q += v * v;
    }
  }
  part[(((ll)g * TCH + tc) * 4 + blockIdx.x) * 256 + threadIdx.x] = make_float2(s, q);
}

__global__ __launch_bounds__(256) void stats_reduce(const float2* __restrict__ part,
                                                    float* __restrict__ meanp,
                                                    float* __restrict__ stdp)
{
  int g  = blockIdx.x >> 2;
  int cc = blockIdx.x & 3;
  int c  = (cc << 8) + threadIdx.x;
  if (c >= ENC) return;
  float s = 0.f, q = 0.f;
  #pragma unroll
  for (int t = 0; t < TCH; ++t) {
    float2 p = part[(((ll)g * TCH + t) * 4 + cc) * 256 + threadIdx.x];
    s += p.x; q += p.y;
  }
  float mn  = s * (1.f / SEQ);
  float var = q * (1.f / SEQ) - mn * mn;
  var = var < 0.f ? 0.f : var;
  meanp[g * ENC + c] = mn;
  stdp [g * ENC + c] = sqrtf(var + 1e-5f);
}

// ------------------------------------------------------------------
__global__ __launch_bounds__(256) void build_xin(const float* __restrict__ x,
                                                 const float* __restrict__ xm,
                                                 const float* __restrict__ meanp,
                                                 const float* __restrict__ stdp,
                                                 u16* __restrict__ xin)
{
  int g  = blockIdx.z;
  int c0 = blockIdx.x << 5, s0 = blockIdx.y << 5;
  __shared__ float tl[32][33];
  __shared__ float mn[32], isd[32];
  int tid = threadIdx.x;
  if (tid < 32) {
    int c = c0 + tid;
    float m = 0.f, s = 1.f;
    if (c < ENC) { m = meanp[g*ENC + c]; s = stdp[g*ENC + c]; }
    mn[tid] = m; isd[tid] = 1.f / s;
  }
  __syncthreads();
  int ci = tid & 31, r = tid >> 5;
  #pragma unroll
  for (int p = 0; p < 4; ++p) {
    int sl = r + (p << 3);
    int s = s0 + sl, c = c0 + ci;
    float v = 0.f;
    if (s < SEQ && c < NTOK) {
      if (c < ENC) v = (x[((ll)g*SEQ + s)*ENC + c] - mn[ci]) * isd[ci];
      else         v = xm[((ll)g*SEQ + s)*4 + (c - ENC)];
    }
    tl[sl][ci] = v;
  }
  __syncthreads();
  int si = tid & 31;
  #pragma unroll
  for (int p = 0; p < 4; ++p) {
    int cl = r + (p << 3);
    int c = c0 + cl;
    if (c < NTOK) xin[((ll)g*NTOK + c)*KPAD + s0 + si] = f2b(tl[si][cl]);
  }
}

// ------------------------------------------------------------------
__global__ __launch_bounds__(256) void pack_embedw(const float* __restrict__ ew,
                                                   u16* __restrict__ wp)
{
  int row = blockIdx.x;
  for (int c = threadIdx.x; c < KPAD; c += 256)
    wp[row*KPAD + c] = (c < SEQ) ? f2b(ew[row*SEQ + c]) : (u16)0;
}

// ------------------------------------------------------------------
__global__ __launch_bounds__(256) void transpose_v(const u16* __restrict__ v, int ldv,
                                                   u16* __restrict__ vT)
{
  int g = blockIdx.z;
  int d0 = blockIdx.x << 5, s0 = blockIdx.y << 5;
  __shared__ u16 tl[32][33];
  int tid = threadIdx.x;
  int di = tid & 31, r = tid >> 5;
  #pragma unroll
  for (int p = 0; p < 4; ++p) {
    int sl = r + (p << 3);
    int s = s0 + sl;
    u16 val = 0;
    if (s < NTOK) val = v[((ll)g*NTOK + s)*ldv + d0 + di];
    tl[sl][di] = val;
  }
  __syncthreads();
  int si = tid & 31;
  #pragma unroll
  for (int p = 0; p < 4; ++p) {
    int dl = r + (p << 3);
    vT[((ll)g*DM + d0 + dl)*SPAD + s0 + si] = tl[si][dl];
  }
}

// ------------------------------------------------------------------
// flash attention, fixed-max softmax (Q pre-scaled by scale*log2e).
// ------------------------------------------------------------------
__global__ __launch_bounds__(256) void flash_attn(const u16* __restrict__ qb,
                                                  const u16* __restrict__ kb,
                                                  int ldqk,
                                                  const u16* __restrict__ vT,
                                                  u16* __restrict__ attb)
{
  const int w = xcd_work();
  const int gh = w / 7;
  const int g = gh >> 3, h = gh & 7;
  const int q0 = (w % 7) * 128;
  const int tid = threadIdx.x, wv = tid >> 6, lane = tid & 63;
  const int q4 = lane >> 4, c16 = lane & 15;
  constexpr int PLD = 136;

  __shared__ __attribute__((aligned(16))) u16 Qs[128*32];
  __shared__ __attribute__((aligned(16))) u16 Ks[128*32];
  __shared__ __attribute__((aligned(16))) u16 Vs[32*PLD];
  __shared__ __attribute__((aligned(16))) u16 Ps[4][32*PLD];

  {
    int r = tid >> 1, sg = (tid & 1) << 4;
    int row = q0 + r; if (row > NTOK-1) row = NTOK-1;
    const u16* src = qb + ((ll)(g*NTOK + row))*ldqk + h*32 + sg;
    *(uint4*)&Qs[r*32 + sg]     = *(const uint4*)src;
    *(uint4*)&Qs[r*32 + sg + 8] = *(const uint4*)(src + 8);
  }
  __syncthreads();

  bf16x8 qf[2];
  qf[0] = as_bf(*(const u16x8*)&Qs[(wv*32 +      c16)*32 + q4*8]);
  qf[1] = as_bf(*(const u16x8*)&Qs[(wv*32 + 16 + c16)*32 + q4*8]);

  float lsum[2][4] = {{0,0,0,0},{0,0,0,0}};
  f32x4 oacc[2][2];
  oacc[0][0] = (f32x4){0,0,0,0}; oacc[0][1] = (f32x4){0,0,0,0};
  oacc[1][0] = (f32x4){0,0,0,0}; oacc[1][1] = (f32x4){0,0,0,0};

  for (int kt = 0; kt < 7; ++kt) {
    const int k0 = kt * 128;
    if (kt) __syncthreads();
    {
      int r = tid >> 1, sg = (tid & 1) << 4;
      int row = k0 + r; if (row > NTOK-1) row = NTOK-1;
      const u16* src = kb + ((ll)(g*NTOK + row))*ldqk + h*32 + sg;
      *(uint4*)&Ks[r*32 + sg]     = *(const uint4*)src;
      *(uint4*)&Ks[r*32 + sg + 8] = *(const uint4*)(src + 8);
    }
    {
      int e = tid >> 3, sg = (tid & 7) << 4;
      const u16* src = vT + ((ll)(g*DM + h*32 + e))*SPAD + k0 + sg;
      *(uint4*)&Vs[e*PLD + sg]     = *(const uint4*)src;
      *(uint4*)&Vs[e*PLD + sg + 8] = *(const uint4*)(src + 8);
    }
    __syncthreads();

    f32x4 s[2][8];
    #pragma unroll
    for (int i = 0; i < 2; ++i)
      #pragma unroll
      for (int j = 0; j < 8; ++j) s[i][j] = (f32x4){0,0,0,0};
    #pragma unroll
    for (int j = 0; j < 8; ++j) {
      bf16x8 kf = as_bf(*(const u16x8*)&Ks[(j*16 + c16)*32 + q4*8]);
      s[0][j] = __builtin_amdgcn_mfma_f32_16x16x32_bf16(qf[0], kf, s[0][j], 0, 0, 0);
      s[1][j] = __builtin_amdgcn_mfma_f32_16x16x32_bf16(qf[1], kf, s[1][j], 0, 0, 0);
    }
    if (kt == 6) {
      #pragma unroll
      for (int j = 0; j < 8; ++j) {
        if (k0 + j*16 + c16 >= NTOK) {
          #pragma unroll
          for (int r = 0; r < 4; ++r) { s[0][j][r] = -1e30f; s[1][j][r] = -1e30f; }
        }
      }
    }

    #pragma unroll
    for (int i = 0; i < 2; ++i)
      #pragma unroll
      for (int j = 0; j < 8; ++j)
        #pragma unroll
        for (int r = 0; r < 4; ++r) {
          float p = exp2f(s[i][j][r]);
          lsum[i][r] += p;
          unsigned u = __builtin_bit_cast(unsigned, p);
          Ps[wv][(i*16 + q4*4 + r)*PLD + j*16 + c16] = (u16)(u >> 16);
        }

    #pragma unroll
    for (int kk = 0; kk < 4; ++kk) {
      bf16x8 af0 = as_bf(*(const u16x8*)&Ps[wv][(     c16)*PLD + kk*32 + q4*8]);
      bf16x8 af1 = as_bf(*(const u16x8*)&Ps[wv][(16 + c16)*PLD + kk*32 + q4*8]);
      bf16x8 b0  = as_bf(*(const u16x8*)&Vs[(     c16)*PLD + kk*32 + q4*8]);
      bf16x8 b1  = as_bf(*(const u16x8*)&Vs[(16 + c16)*PLD + kk*32 + q4*8]);
      oacc[0][0] = __builtin_amdgcn_mfma_f32_16x16x32_bf16(af0, b0, oacc[0][0], 0, 0, 0);
      oacc[0][1] = __builtin_amdgcn_mfma_f32_16x16x32_bf16(af0, b1, oacc[0][1], 0, 0, 0);
      oacc[1][0] = __builtin_amdgcn_mfma_f32_16x16x32_bf16(af1, b0, oacc[1][0], 0, 0, 0);
      oacc[1][1] = __builtin_amdgcn_mfma_f32_16x16x32_bf16(af1, b1, oacc[1][1], 0, 0, 0);
    }
  }

  float linv[2][4];
  #pragma unroll
  for (int i = 0; i < 2; ++i)
    #pragma unroll
    for (int r = 0; r < 4; ++r) {
      float t = lsum[i][r];
      t += __shfl_xor(t, 1, 64);
      t += __shfl_xor(t, 2, 64);
      t += __shfl_xor(t, 4, 64);
      t += __shfl_xor(t, 8, 64);
      linv[i][r] = 1.f / t;
    }
  #pragma unroll
  for (int i = 0; i < 2; ++i)
    #pragma unroll
    for (int jn = 0; jn < 2; ++jn)
      #pragma unroll
      for (int r = 0; r < 4; ++r) {
        int row = q0 + wv*32 + i*16 + q4*4 + r;
        if (row < NTOK)
          attb[((ll)(g*NTOK + row))*DM + h*32 + jn*16 + c16] =
            f2b(oacc[i][jn][r] * linv[i][r]);
      }
}

// ------------------------------------------------------------------
__global__ __launch_bounds__(256) void ln_rows(const u16* __restrict__ in1,
                                               const u16* __restrict__ in2,
                                               int ld1, int ld2,
                                               const float* __restrict__ gamma,
                                               const float* __restrict__ beta,
                                               u16* __restrict__ out, int ldo, int Mrows)
{
  int row = blockIdx.x*4 + (threadIdx.x >> 6);
  int lane = threadIdx.x & 63;
  if (row >= Mrows) return;
  float xv[4];
  ushort4 a = *(const ushort4*)(in1 + (ll)row*ld1 + lane*4);
  xv[0]=b2f(a.x); xv[1]=b2f(a.y); xv[2]=b2f(a.z); xv[3]=b2f(a.w);
  if (in2) {
    ushort4 b = *(const ushort4*)(in2 + (ll)row*ld2 + lane*4);
    xv[0]-=b2f(b.x); xv[1]-=b2f(b.y); xv[2]-=b2f(b.z); xv[3]-=b2f(b.w);
  }
  float s = xv[0]+xv[1]+xv[2]+xv[3];
  #pragma unroll
  for (int o = 32; o > 0; o >>= 1) s += __shfl_xor(s, o, 64);
  float mean = s * (1.f/256.f);
  float d0=xv[0]-mean, d1=xv[1]-mean, d2=xv[2]-mean, d3=xv[3]-mean;
  float q = d0*d0 + d1*d1 + d2*d2 + d3*d3;
  #pragma unroll
  for (int o = 32; o > 0; o >>= 1) q += __shfl_xor(q, o, 64);
  float rstd = 1.f / sqrtf(q * (1.f/256.f) + 1e-5f);
  float4 gv = *(const float4*)(gamma + lane*4);
  float4 bb = *(const float4*)(beta  + lane*4);
  ushort4 o4;
  o4.x = f2b(d0*rstd*gv.x + bb.x);
  o4.y = f2b(d1*rstd*gv.y + bb.y);
  o4.z = f2b(d2*rstd*gv.z + bb.z);
  o4.w = f2b(d3*rstd*gv.w + bb.w);
  *(ushort4*)(out + (ll)row*ldo + lane*4) = o4;
}

// ------------------------------------------------------------------
__global__ __launch_bounds__(256) void final_combine(const u16* __restrict__ outF,
                                                     const float* __restrict__ meanp,
                                                     const float* __restrict__ stdp,
                                                     float* __restrict__ dout)
{
  int b = blockIdx.z;
  int c0 = blockIdx.x << 5, s0 = blockIdx.y << 5;
  __shared__ float tl[32][33];
  int tid = threadIdx.x;
  int si = tid & 31, r = tid >> 5;
  #pragma unroll
  for (int p = 0; p < 4; ++p) {
    int cl = r + (p << 3);
    int c = c0 + cl, s = s0 + si;
    float accv = 0.f;
    #pragma unroll
    for (int t = 0; t < 2; ++t) {
      int g = b*2 + t;
      if (c < ENC && s < SEQ) {
        float v = b2f(outF[((ll)(g*NTOK + c))*SEQ + s]);
        accv += 0.5f * (v * stdp[g*ENC + c] + meanp[g*ENC + c]);
      }
    }
    tl[cl][si] = accv;
  }
  __syncthreads();
  int ci = tid & 31;
  #pragma unroll
  for (int p = 0; p < 4; ++p) {
    int sl = r + (p << 3);
    int s = s0 + sl, c = c0 + ci;
    if (s < SEQ && c < ENC)
      dout[((ll)b*SEQ + s)*ENC + c] = tl[ci][sl];
  }
}

// ------------------------------------------------------------------
// Pipelined 64x64-tile NT GEMM, K-step 64 (two 32-wide panels),
// double-buffered LDS, raw s_barrier + counted vmcnt (T3/T4 recipe).
// Conflict-free XOR swizzle both sides (rule #21, verified r5: 0 conflicts).
// NB=1: modes 0 store / 1 gelu / 2 store+sub / 5 qkv. 32 KiB, 5 blk/CU.
// NB=2: 48 KiB, 3 blk/CU (used for W3/W4: N=256 keeps block count high).
// ------------------------------------------------------------------
template<int NB>
__global__ __launch_bounds__(256, NB == 1 ? 5 : 3) void gemm64(
    const u16* __restrict__ A, const u16* __restrict__ B0, const u16* __restrict__ B1,
    const float* __restrict__ bias0, const float* __restrict__ bias1,
    u16* __restrict__ C,
    const u16* __restrict__ aux1, u16* __restrict__ aux2, const u16* __restrict__ sub,
    int M, int N, int K, int lda, int ldb, int ldc, int ld1, int ld2, int ldsub, int mode)
{
  // [buf p][panel c] tiles of 64 rows x 32 cols, row-major ld=32
  __shared__ __attribute__((aligned(16))) u16 S[8192 * (1 + NB)];

  const int tid  = threadIdx.x;
  const int wv   = tid >> 6;
  const int lane = tid & 63;
  const int q4   = lane >> 4;
  const int c16  = lane & 15;

  const int w  = xcd_work();
  const int n0 = (w % gridDim.x) * 64;
  const int m0 = (w / gridDim.x) * 64;
  const int wm = (wv >> 1) * 32;
  const int wn = (wv & 1) * 32;

  // staging: 16 rows x 64 B per g2l; source chunk pre-swizzled so the
  // linear LDS write produces the XOR-swizzled layout
  const int lrow = lane >> 2;                                   // 0..15
  const int lcol = (((lane & 3) ^ ((lrow >> 1) & 3)) << 3);     // u16 offset

  int arow = m0 + wv*16 + lrow; if (arow >= M) arow = M-1;
  int brow = n0 + wv*16 + lrow; if (brow >= N) brow = N-1;
  const u16* pa  = A  + (ll)arow*lda + lcol;
  const u16* pb0 = B0 + (ll)brow*ldb + lcol;
  const u16* pb1 = (NB == 2) ? B1 + (ll)brow*ldb + lcol : nullptr;

  f32x4 acc0[2][2];
  f32x4 acc1[2][2];
  #pragma unroll
  for (int i = 0; i < 2; ++i)
    #pragma unroll
    for (int j = 0; j < 2; ++j) {
      acc0[i][j] = (f32x4){0,0,0,0};
      if constexpr (NB == 2) acc1[i][j] = (f32x4){0,0,0,0};
    }

  const int nk = K >> 6;
  auto issue = [&](int kt2, int p) {
    const int ko = kt2 * 64;
    #pragma unroll
    for (int c = 0; c < 2; ++c) {
      g2l(pa  + ko + c*32, &S[(p*2 + c)*2048 + (wv*16)*32]);
      g2l(pb0 + ko + c*32, &S[8192 + (p*2 + c)*2048 + (wv*16)*32]);
      if constexpr (NB == 2)
        g2l(pb1 + ko + c*32, &S[16384 + (p*2 + c)*2048 + (wv*16)*32]);
    }
  };

  issue(0, 0);
  for (int kt = 0; kt < nk; ++kt) {
    const int p = kt & 1;
    if (kt + 1 < nk) {
      issue(kt + 1, p ^ 1);
      // counted wait: just-issued loads (4 or 6) stay in flight
      if constexpr (NB == 1) asm volatile("s_waitcnt vmcnt(4)" ::: "memory");
      else                   asm volatile("s_waitcnt vmcnt(6)" ::: "memory");
    } else {
      asm volatile("s_waitcnt vmcnt(0)" ::: "memory");
    }
    __builtin_amdgcn_s_barrier();
    asm volatile("" ::: "memory");

    const int sw = ((q4 ^ ((c16 >> 1) & 3)) << 3);  // swizzled read chunk
    #pragma unroll
    for (int c = 0; c < 2; ++c) {
      const u16* as_ = &S[(p*2 + c)*2048];
      const u16* b0s = &S[8192 + (p*2 + c)*2048];
      bf16x8 af[2], bfv[2];
      #pragma unroll
      for (int i = 0; i < 2; ++i)
        af[i] = as_bf(*(const u16x8*)&as_[(wm + i*16 + c16)*32 + sw]);
      #pragma unroll
      for (int j = 0; j < 2; ++j)
        bfv[j] = as_bf(*(const u16x8*)&b0s[(wn + j*16 + c16)*32 + sw]);
      #pragma unroll
      for (int i = 0; i < 2; ++i)
        #pragma unroll
        for (int j = 0; j < 2; ++j)
          acc0[i][j] = __builtin_amdgcn_mfma_f32_16x16x32_bf16(af[i], bfv[j], acc0[i][j], 0, 0, 0);
      if constexpr (NB == 2) {
        const u16* b1s = &S[16384 + (p*2 + c)*2048];
        bf16x8 b1v[2];
        #pragma unroll
        for (int j = 0; j < 2; ++j)
          b1v[j] = as_bf(*(const u16x8*)&b1s[(wn + j*16 + c16)*32 + sw]);
        #pragma unroll
        for (int i = 0; i < 2; ++i)
          #pragma unroll
          for (int j = 0; j < 2; ++j)
            acc1[i][j] = __builtin_amdgcn_mfma_f32_16x16x32_bf16(af[i], b1v[j], acc1[i][j], 0, 0, 0);
      }
    }

    asm volatile("s_waitcnt lgkmcnt(0)" ::: "memory");
    __builtin_amdgcn_s_barrier();
  }

  #pragma unroll
  for (int i = 0; i < 2; ++i) {
    #pragma unroll
    for (int j = 0; j < 2; ++j) {
      int n = n0 + wn + j*16 + c16;
      if (n >= N) continue;
      float bv0 = bias0 ? bias0[n] : 0.f;
      float bv1 = (NB == 2) ? bias1[n] : 0.f;
      int mb = m0 + wm + i*16 + q4*4;
      #pragma unroll
      for (int r = 0; r < 4; ++r) {
        int m = mb + r;
        if (m >= M) continue;
        ll ci = (ll)m*ldc + n;
        if constexpr (NB == 2) {
          float z5 = acc0[i][j][r] + bv0;
          float z6 = acc1[i][j][r] + bv1;
          float v = z6 / (1.f + expf(-z5));
          if (sub) v -= b2f(sub[(ll)m*ldsub + n]);
          C[ci] = f2b(v);
        } else {
          float x = acc0[i][j][r] + bv0;
          if (mode == 0) {
            C[ci] = f2b(x);
          } else if (mode == 1) {
            C[ci] = f2b(0.5f * x * (1.f + erff(x * 0.70710678118654752f)));
          } else if (mode == 5) {
            C[ci] = f2b(n < 256 ? x * SC2 : x);
          } else { // mode 2
            C[ci] = f2b(x);
            float xl = b2f(aux1[(ll)m*ld1 + n]);
            aux2[(ll)m*ld2 + n] = f2b(xl - x);
          }
        }
      }
    }
  }
}

// ------------------------------------------------------------------
// 128x64-tile dual-B NT GEMM for W5/W6, BK=32, THREE-buffer LDS ring.
// r6 measured this geometry (2-buf) at 61.0 us with MfmaUtil 13.5%,
// occupancy 26%, conflicts 0, nothing saturated -- the m233 2-phase
// signature (stage+vmcnt+barrier convoy). The untested axis is prefetch
// DEPTH: 2-buf waits on loads issued only ONE step (~500cy) earlier,
// so any L2-miss (~200-900cy) stalls every step. 3-ring prefetches TWO
// steps ahead; steady-state s_waitcnt vmcnt(8) leaves 8 loads in flight
// spanning two barriers (T4 mechanism, m218).
// Waves 2Mx2N, wave tile 64x32 of BOTH outputs (8 ds_read -> 16 MFMA).
// LDS 48 KiB (3 x 16 KiB) -> 3 blk/CU; launch_bounds(256,3).
// Same verified XOR swizzle; accumulation order unchanged (BK=32 seq).
// C = sig(A B0^T + b0) * (A B1^T + b1) [- sub].
// ------------------------------------------------------------------
__global__ __launch_bounds__(256, 3) void gemm128d(
    const u16* __restrict__ A, const u16* __restrict__ B0, const u16* __restrict__ B1,
    const float* __restrict__ bias0, const float* __restrict__ bias1,
    u16* __restrict__ C, const u16* __restrict__ sub,
    int M, int N, int K, int lda, int ldb, int ldc, int ldsub)
{
  // A: 3 bufs x (128x32) = 12288 u16; B0: 3 x (64x32) = 6144 @12288;
  // B1: 6144 @18432. Total 24576 u16 = 48 KiB.
  __shared__ __attribute__((aligned(16))) u16 S[24576];

  const int tid  = threadIdx.x;
  const int wv   = tid >> 6;
  const int lane = tid & 63;
  const int q4   = lane >> 4;
  const int c16  = lane & 15;

  const int w  = xcd_work();
  const int n0 = (w % gridDim.x) * 64;
  const int m0 = (w / gridDim.x) * 128;
  const int wm = (wv >> 1) * 64;
  const int wn = (wv & 1) * 32;

  const int lrow = lane >> 2;                                   // 0..15
  const int lcol = (((lane & 3) ^ ((lrow >> 1) & 3)) << 3);     // pre-swizzled src

  int ar0 = m0 + wv*32 + lrow;      if (ar0 >= M) ar0 = M-1;
  int ar1 = m0 + wv*32 + 16 + lrow; if (ar1 >= M) ar1 = M-1;
  int br  = n0 + wv*16 + lrow;      if (br  >= N) br  = N-1;
  const u16* pa0 = A  + (ll)ar0*lda + lcol;
  const u16* pa1 = A  + (ll)ar1*lda + lcol;
  const u16* pb0 = B0 + (ll)br*ldb + lcol;
  const u16* pb1 = B1 + (ll)br*ldb + lcol;

  f32x4 acc0[4][2], acc1[4][2];
  #pragma unroll
  for (int i = 0; i < 4; ++i)
    #pragma unroll
    for (int j = 0; j < 2; ++j) {
      acc0[i][j] = (f32x4){0,0,0,0};
      acc1[i][j] = (f32x4){0,0,0,0};
    }

  const int nk = K >> 5;          // BK=32; nk = 16 for K=512
  auto issue = [&](int kt2) {
    const int p  = kt2 % 3;
    const int ko = kt2 * 32;
    g2l(pa0 + ko, &S[p*4096 + (wv*32)*32]);
    g2l(pa1 + ko, &S[p*4096 + (wv*32 + 16)*32]);
    g2l(pb0 + ko, &S[12288 + p*2048 + (wv*16)*32]);
    g2l(pb1 + ko, &S[18432 + p*2048 + (wv*16)*32]);
  };

  issue(0);
  issue(1);
  for (int kt = 0; kt < nk; ++kt) {
    const int p = kt % 3;
    if (kt + 2 < nk) {
      issue(kt + 2);
      // buffers kt+1 (4 loads) and kt+2 (4 loads) stay in flight
      asm volatile("s_waitcnt vmcnt(8)" ::: "memory");
    } else if (kt + 1 < nk) {
      asm volatile("s_waitcnt vmcnt(4)" ::: "memory");
    } else {
      asm volatile("s_waitcnt vmcnt(0)" ::: "memory");
    }
    __builtin_amdgcn_s_barrier();
    asm volatile("" ::: "memory");

    const int sw = ((q4 ^ ((c16 >> 1) & 3)) << 3);
    const u16* as_ = &S[p*4096];
    const u16* b0s = &S[12288 + p*2048];
    const u16* b1s = &S[18432 + p*2048];
    bf16x8 af[4], b0v[2], b1v[2];
    #pragma unroll
    for (int i = 0; i < 4; ++i)
      af[i] = as_bf(*(const u16x8*)&as_[(wm + i*16 + c16)*32 + sw]);
    #pragma unroll
    for (int j = 0; j < 2; ++j) {
      b0v[j] = as_bf(*(const u16x8*)&b0s[(wn + j*16 + c16)*32 + sw]);
      b1v[j] = as_bf(*(const u16x8*)&b1s[(wn + j*16 + c16)*32 + sw]);
    }
    #pragma unroll
    for (int i = 0; i < 4; ++i)
      #pragma unroll
      for (int j = 0; j < 2; ++j) {
        acc0[i][j] = __builtin_amdgcn_mfma_f32_16x16x32_bf16(af[i], b0v[j], acc0[i][j], 0, 0, 0);
        acc1[i][j] = __builtin_amdgcn_mfma_f32_16x16x32_bf16(af[i], b1v[j], acc1[i][j], 0, 0, 0);
      }

    asm volatile("s_waitcnt lgkmcnt(0)" ::: "memory");
    __builtin_amdgcn_s_barrier();
  }

  #pragma unroll
  for (int i = 0; i < 4; ++i) {
    #pragma unroll
    for (int j = 0; j < 2; ++j) {
      int n = n0 + wn + j*16 + c16;
      if (n >= N) continue;
      float bv0 = bias0[n], bv1 = bias1[n];
      int mb = m0 + wm + i*16 + q4*4;
      #pragma unroll
      for (int r = 0; r < 4; ++r) {
        int m = mb + r;
        if (m >= M) continue;
        float z5 = acc0[i][j][r] + bv0;
        float z6 = acc1[i][j][r] + bv1;
        float v = z6 / (1.f + expf(-z5));
        if (sub) v -= b2f(sub[(ll)m*ldsub + n]);
        C[(ll)m*ldc + n] = f2b(v);
      }
    }
  }
}

// ------------------------------------------------------------------
extern "C" void kernel_launch(void* const* d_in, const int* in_sizes, int n_in,
                              void* d_out, int out_size, void* d_ws, size_t ws_size,
                              hipStream_t stream)
{
  (void)in_sizes; (void)n_in; (void)out_size; (void)ws_size;
  const float* x    = (const float*)d_in[0];
  const float* xm   = (const float*)d_in[1];
  const float* embw = (const float*)d_in[4];
  const float* embb = (const float*)d_in[5];
  const float* Wqf  = (const float*)d_in[6];
  const float* Wkf  = (const float*)d_in[7];
  const float* Wvf  = (const float*)d_in[8];
  const float* Wof  = (const float*)d_in[9];
  const float* W3f  = (const float*)d_in[10];
  const float* W4f  = (const float*)d_in[11];
  const float* bq   = (const float*)d_in[12];
  const float* bk   = (const float*)d_in[13];
  const float* bv   = (const float*)d_in[14];
  const float* bo   = (const float*)d_in[15];
  const float* b3   = (const float*)d_in[16];
  const float* b4   = (const float*)d_in[17];
  const float* W1f  = (const float*)d_in[18];
  const float* b1   = (const float*)d_in[19];
  const float* W2f  = (const float*)d_in[20];
  const float* b2   = (const float*)d_in[21];
  const float* W5f  = (const float*)d_in[22];
  const float* b5   = (const float*)d_in[23];
  const float* W6f  = (const float*)d_in[24];
  const float* b6   = (const float*)d_in[25];
  const float* ln1g = (const float*)d_in[26];
  const float* ln1b = (const float*)d_in[27];
  const float* ln2g = (const float*)d_in[28];
  const float* ln2b = (const float*)d_in[29];

  u8* ws = (u8*)d_ws;
  size_t off = 0;
  auto alloc = [&](size_t bytes) -> void* {
    void* ptr = ws + off;
    off = (off + bytes + 255) & ~(size_t)255;
    return ptr;
  };
  float* meanp = (float*)alloc((size_t)G16*ENC*4);
  float* stdp  = (float*)alloc((size_t)G16*ENC*4);
  float* partp = (float*)alloc((size_t)G16*TCH*1024*2*4);
  u16* xin   = (u16*)alloc((size_t)G16*NTOK*KPAD*2);
  u16* wp    = (u16*)alloc((size_t)DM*KPAD*2);
  const int nWsm = 2*DM*DM;
  const int nWff = 2*512*DM;
  const int nW56 = 2*SEQ*512;
  u16* Wqkv = (u16*)alloc((size_t)2*768*256*2);
  u16* Wo = (u16*)alloc((size_t)nWsm*2);
  u16* W3 = (u16*)alloc((size_t)nWsm*2);
  u16* W4 = (u16*)alloc((size_t)nWsm*2);
  u16* W1 = (u16*)alloc((size_t)nWff*2);
  u16* W2 = (u16*)alloc((size_t)nWff*2);
  u16* W5 = (u16*)alloc((size_t)nW56*2);
  u16* W6 = (u16*)alloc((size_t)nW56*2);
  float* bqkv = (float*)alloc((size_t)2*768*4);
  u16* hb    = (u16*)alloc((size_t)MTOT*DM*2);
  u16* qkvb  = (u16*)alloc((size_t)MTOT*768*2);
  u16* vT    = (u16*)alloc((size_t)G16*DM*SPAD*2);
  u16* attb  = (u16*)alloc((size_t)MTOT*DM*2);
  u16* catb  = (u16*)alloc((size_t)MTOT*512*2);
  u16* xlnb  = (u16*)alloc((size_t)MTOT*DM*2);
  u16* t1b   = (u16*)alloc((size_t)MTOT*512*2);
  u16* xsb   = (u16*)alloc((size_t)MTOT*DM*2);
  u16* hhb   = (u16*)alloc((size_t)MTOT*DM*2);
  u16* out0b = (u16*)alloc((size_t)MTOT*SEQ*2);
  u16* outFb = (u16*)alloc((size_t)MTOT*SEQ*2);

  // pipelined 64x64 single-B gemm
  auto gemm64_1 = [&](const u16* A, int lda, const u16* B, int ldb, const float* bias,
                      u16* C, int ldc, int M, int N, int K, int mode,
                      const u16* a1, int ld1, u16* a2, int ld2) {
    dim3 grid((N + 63) / 64, (M + 63) / 64, 1);
    gemm64<1><<<grid, 256, 0, stream>>>(A, B, nullptr, bias, nullptr, C, a1, a2, nullptr,
                                        M, N, K, lda, ldb, ldc, ld1, ld2, 0, mode);
  };
  // pipelined 64x64 dual-B gemm (glu) -- W3/W4 (N=256)
  auto gemm64_2 = [&](const u16* A, int lda, const u16* B0p, const u16* B1p, int ldb,
                      const float* bias0, const float* bias1, u16* C, int ldc,
                      const u16* sub, int ldsub, int M, int N, int K) {
    dim3 grid((N + 63) / 64, (M + 63) / 64, 1);
    gemm64<2><<<grid, 256, 0, stream>>>(A, B0p, B1p, bias0, bias1, C, nullptr, nullptr, sub,
                                        M, N, K, lda, ldb, ldc, 0, 0, ldsub, 0);
  };
  // 128x64 dual-B gemm, 3-buffer ring -- W5/W6 (N=720, K=512)
  auto gemmD128 = [&](const u16* A, int lda, const u16* B0p, const u16* B1p, int ldb,
                      const float* bias0, const float* bias1, u16* C, int ldc,
                      const u16* sub, int ldsub, int M, int N, int K) {
    dim3 grid((N + 63) / 64, (M + 127) / 128, 1);
    gemm128d<<<grid, 256, 0, stream>>>(A, B0p, B1p, bias0, bias1, C, sub,
                                       M, N, K, lda, ldb, ldc, ldsub);
  };

  // weight conversion: one launch, 10 jobs
  CvtJobs J{};
  int nj = 0;
  auto addjob = [&](const float* s, u16* d, int n, int per, ll stride) {
    J.src[nj] = s; J.dst[nj] = d; J.n[nj] = n; J.per[nj] = per; J.stride[nj] = stride; nj++;
  };
  addjob(Wqf, Wqkv,           nWsm, 65536, 196608);
  addjob(Wkf, Wqkv + 65536,   nWsm, 65536, 196608);
  addjob(Wvf, Wqkv + 131072,  nWsm, 65536, 196608);
  addjob(Wof, Wo, nWsm, 0, 0);
  addjob(W3f, W3, nWsm, 0, 0);
  addjob(W4f, W4, nWsm, 0, 0);
  addjob(W1f, W1, nWff, 0, 0);
  addjob(W2f, W2, nWff, 0, 0);
  addjob(W5f, W5, nW56, 0, 0);
  addjob(W6f, W6, nW56, 0, 0);
  cvt_multi<<<dim3(512, 10), 256, 0, stream>>>(J);
  pack_bqkv<<<6, 256, 0, stream>>>(bq, bk, bv, bqkv);

  stats_part<<<dim3(4, TCH, 16), 256, 0, stream>>>(x, (float2*)partp);
  stats_reduce<<<64, 256, 0, stream>>>((const float2*)partp, meanp, stdp);
  build_xin<<<dim3(28, 24, 16), 256, 0, stream>>>(x, xm, meanp, stdp, xin);
  pack_embedw<<<256, 256, 0, stream>>>(embw, wp);

  // h = xin @ embed_w^T + embed_b
  gemm64_1(xin, KPAD, wp, KPAD, embb, hb, DM, MTOT, DM, KPAD, 0, nullptr, 0, nullptr, 0);

  for (int l = 0; l < 2; ++l) {
    const ll wOff = (ll)l * DM * DM;
    // fused qkv (q pre-scaled by scale*log2e)
    gemm64_1(hb, DM, Wqkv + (ll)l*768*256, 256, bqkv + l*768, qkvb, 768,
             MTOT, 768, DM, 5, nullptr, 0, nullptr, 0);
    transpose_v<<<dim3(8, 28, 16), 256, 0, stream>>>(qkvb + 512, 768, vT);

    flash_attn<<<dim3(7, 128), 256, 0, stream>>>(qkvb, qkvb + 256, 768, vT, attb);

    // x_att -> cat[:, 0:256]
    gemm64_1(attb, DM, Wo + wOff, DM, bo + l*DM, catb, 512, MTOT, DM, DM, 0, nullptr, 0, nullptr, 0);
    // x_ln = LN(h - x_att)
    ln_rows<<<MTOT/4, 256, 0, stream>>>(hb, catb, DM, 512, ln1g + l*DM, ln1b + l*DM, xlnb, DM, MTOT);
    // t1 = gelu(x_ln @ W1^T + b1)
    gemm64_1(xlnb, DM, W1 + (ll)l*512*DM, DM, b1 + l*512, t1b, 512, MTOT, 512, DM, 1, nullptr, 0, nullptr, 0);
    // y -> cat[:, 256:512]; xs = x_ln - y
    gemm64_1(t1b, 512, W2 + (ll)l*DM*512, 512, b2 + l*DM, catb + 256, 512, MTOT, DM, 512, 2, xlnb, DM, xsb, DM);
    // hh = sigmoid(xs W3^T + b3) * (xs W4^T + b4)
    gemm64_2(xsb, DM, W3 + wOff, W4 + wOff, DM, b3 + l*DM, b4 + l*DM, hhb, DM,
             nullptr, 0, MTOT, DM, DM);
    // h = LN(hh)
    ln_rows<<<MTOT/4, 256, 0, stream>>>(hhb, nullptr, DM, 0, ln2g + l*DM, ln2b + l*DM, hb, DM, MTOT);
    // out = sigmoid(cat W5^T + b5) * (cat W6^T + b6)  [- out0 on layer 1]
    if (l == 0)
      gemmD128(catb, 512, W5 + (ll)l*SEQ*512, W6 + (ll)l*SEQ*512, 512,
               b5 + l*SEQ, b6 + l*SEQ, out0b, SEQ, nullptr, 0, MTOT, SEQ, 512);
    else
      gemmD128(catb, 512, W5 + (ll)l*SEQ*512, W6 + (ll)l*SEQ*512, 512,
               b5 + l*SEQ, b6 + l*SEQ, outFb, SEQ, out0b, SEQ, MTOT, SEQ, 512);
  }

  final_combine<<<dim3(27, 23, 8), 256, 0, stream>>>(outFb, meanp, stdp, (float*)d_out);
}

// Round 10
// 597.615 us; speedup vs baseline: 1.2707x; 1.0221x over previous
//
#include <hip/hip_runtime.h>
#include <cstdint>
#include <cstddef>

#define DEV __device__ __forceinline__
#define AS1 __attribute__((address_space(1)))
#define AS3 __attribute__((address_space(3)))

typedef unsigned short u16;
typedef unsigned char u8;
typedef long long ll;

typedef __attribute__((ext_vector_type(8))) __bf16 bf16x8;
typedef __attribute__((ext_vector_type(8))) unsigned short u16x8;
typedef __attribute__((ext_vector_type(4))) float f32x4;

static constexpr int SEQ  = 720;
static constexpr int ENC  = 862;
static constexpr int NTOK = 866;            // ENC + MARK
static constexpr int DM   = 256;
static constexpr int G16  = 16;             // B * T_SCALES
static constexpr int MTOT = G16 * NTOK;     // 13856
static constexpr int KPAD = 768;            // SEQ padded to multiple of 64
static constexpr int SPAD = 896;            // 866 keys padded to multiple of 32
static constexpr int TCH  = 15;             // time chunks for stats (720 = 15*48)
static constexpr float SC2 = 0.17677669529663689f * 1.4426950408889634f; // scale*log2e

DEV float b2f(u16 v){ union { unsigned u; float f; } x; x.u = ((unsigned)v) << 16; return x.f; }
DEV u16 f2b(float f){ union { float f; unsigned u; } x; x.f = f;
  unsigned r = x.u + 0x7fffu + ((x.u >> 16) & 1u); return (u16)(r >> 16); }
DEV bf16x8 as_bf(u16x8 v){ return __builtin_bit_cast(bf16x8, v); }

// async global->LDS, 16B per lane; LDS base wave-uniform
DEV void g2l(const u16* g, u16* l){
  __builtin_amdgcn_global_load_lds((AS1 void*)g, (AS3 void*)l, 16, 0, 0);
}

// XCD-aware remap: XCD (L%8) owns a contiguous band of work-items
DEV int xcd_work(){
  int L = blockIdx.y * gridDim.x + blockIdx.x;
  int T = gridDim.x * gridDim.y;
  int x = L & 7, k = L >> 3;
  int q = T >> 3, r = T & 7;
  int mn = x < r ? x : r;
  return x*q + mn + k;
}

// ------------------------------------------------------------------
struct CvtJobs {
  const float* src[10];
  u16* dst[10];
  int n[10];
  int per[10];
  ll stride[10];
};
__global__ __launch_bounds__(256) void cvt_multi(CvtJobs J)
{
  int j = blockIdx.y;
  const float* s = J.src[j];
  u16* d = J.dst[j];
  int n = J.n[j], per = J.per[j];
  ll st = J.stride[j];
  for (int i = blockIdx.x*256 + threadIdx.x; i < n; i += gridDim.x*256) {
    ll di = per ? ((ll)(i/per)*st + (i%per)) : (ll)i;
    d[di] = f2b(s[i]);
  }
}

__global__ __launch_bounds__(256) void pack_bqkv(const float* __restrict__ bq,
                                                 const float* __restrict__ bk,
                                                 const float* __restrict__ bv,
                                                 float* __restrict__ out)
{
  int idx = blockIdx.x*256 + threadIdx.x;
  if (idx >= 1536) return;
  int l = idx / 768, j = idx % 768;
  float v;
  if (j < 256)      v = bq[l*256 + j];
  else if (j < 512) v = bk[l*256 + j - 256];
  else              v = bv[l*256 + j - 512];
  out[idx] = v;
}

// ------------------------------------------------------------------
// per-(group, column) mean/std over SEQ, two-pass deterministic.
// ------------------------------------------------------------------
__global__ __launch_bounds__(256) void stats_part(const float* __restrict__ x,
                                                  float2* __restrict__ part)
{
  int g  = blockIdx.z;
  int tc = blockIdx.y;
  int c  = (blockIdx.x << 8) + threadIdx.x;
  float s = 0.f, q = 0.f;
  if (c < ENC) {
    const float* xp = x + ((ll)g * SEQ + tc * 48) * ENC + c;
    #pragma unroll 8
    for (int t = 0; t < 48; ++t) {
      float v = xp[(ll)t * ENC];
      s += v; q += v * v;
    }
  }
  part[(((ll)g * TCH + tc) * 4 + blockIdx.x) * 256 + threadIdx.x] = make_float2(s, q);
}

__global__ __launch_bounds__(256) void stats_reduce(const float2* __restrict__ part,
                                                    float* __restrict__ meanp,
                                                    float* __restrict__ stdp)
{
  int g  = blockIdx.x >> 2;
  int cc = blockIdx.x & 3;
  int c  = (cc << 8) + threadIdx.x;
  if (c >= ENC) return;
  float s = 0.f, q = 0.f;
  #pragma unroll
  for (int t = 0; t < TCH; ++t) {
    float2 p = part[(((ll)g * TCH + t) * 4 + cc) * 256 + threadIdx.x];
    s += p.x; q += p.y;
  }
  float mn  = s * (1.f / SEQ);
  float var = q * (1.f / SEQ) - mn * mn;
  var = var < 0.f ? 0.f : var;
  meanp[g * ENC + c] = mn;
  stdp [g * ENC + c] = sqrtf(var + 1e-5f);
}

// ------------------------------------------------------------------
__global__ __launch_bounds__(256) void build_xin(const float* __restrict__ x,
                                                 const float* __restrict__ xm,
                                                 const float* __restrict__ meanp,
                                                 const float* __restrict__ stdp,
                                                 u16* __restrict__ xin)
{
  int g  = blockIdx.z;
  int c0 = blockIdx.x << 5, s0 = blockIdx.y << 5;
  __shared__ float tl[32][33];
  __shared__ float mn[32], isd[32];
  int tid = threadIdx.x;
  if (tid < 32) {
    int c = c0 + tid;
    float m = 0.f, s = 1.f;
    if (c < ENC) { m = meanp[g*ENC + c]; s = stdp[g*ENC + c]; }
    mn[tid] = m; isd[tid] = 1.f / s;
  }
  __syncthreads();
  int ci = tid & 31, r = tid >> 5;
  #pragma unroll
  for (int p = 0; p < 4; ++p) {
    int sl = r + (p << 3);
    int s = s0 + sl, c = c0 + ci;
    float v = 0.f;
    if (s < SEQ && c < NTOK) {
      if (c < ENC) v = (x[((ll)g*SEQ + s)*ENC + c] - mn[ci]) * isd[ci];
      else         v = xm[((ll)g*SEQ + s)*4 + (c - ENC)];
    }
    tl[sl][ci] = v;
  }
  __syncthreads();
  int si = tid & 31;
  #pragma unroll
  for (int p = 0; p < 4; ++p) {
    int cl = r + (p << 3);
    int c = c0 + cl;
    if (c < NTOK) xin[((ll)g*NTOK + c)*KPAD + s0 + si] = f2b(tl[si][cl]);
  }
}

// ------------------------------------------------------------------
__global__ __launch_bounds__(256) void pack_embedw(const float* __restrict__ ew,
                                                   u16* __restrict__ wp)
{
  int row = blockIdx.x;
  for (int c = threadIdx.x; c < KPAD; c += 256)
    wp[row*KPAD + c] = (c < SEQ) ? f2b(ew[row*SEQ + c]) : (u16)0;
}

// ------------------------------------------------------------------
__global__ __launch_bounds__(256) void transpose_v(const u16* __restrict__ v, int ldv,
                                                   u16* __restrict__ vT)
{
  int g = blockIdx.z;
  int d0 = blockIdx.x << 5, s0 = blockIdx.y << 5;
  __shared__ u16 tl[32][33];
  int tid = threadIdx.x;
  int di = tid & 31, r = tid >> 5;
  #pragma unroll
  for (int p = 0; p < 4; ++p) {
    int sl = r + (p << 3);
    int s = s0 + sl;
    u16 val = 0;
    if (s < NTOK) val = v[((ll)g*NTOK + s)*ldv + d0 + di];
    tl[sl][di] = val;
  }
  __syncthreads();
  int si = tid & 31;
  #pragma unroll
  for (int p = 0; p < 4; ++p) {
    int dl = r + (p << 3);
    vT[((ll)g*DM + d0 + dl)*SPAD + s0 + si] = tl[si][dl];
  }
}

// ------------------------------------------------------------------
// flash attention, fixed-max softmax (Q pre-scaled by scale*log2e).
// T14 async-STAGE split: next tile's K/V prefetched into REGISTERS
// during the current tile's compute (issue-early / write-late, +17%
// attn in m214v27); named regs = static indexing (rule #20).
// T5 setprio(1) around MFMA clusters (+4-7% attn, m191).
// ------------------------------------------------------------------
__global__ __launch_bounds__(256) void flash_attn(const u16* __restrict__ qb,
                                                  const u16* __restrict__ kb,
                                                  int ldqk,
                                                  const u16* __restrict__ vT,
                                                  u16* __restrict__ attb)
{
  const int w = xcd_work();
  const int gh = w / 7;
  const int g = gh >> 3, h = gh & 7;
  const int q0 = (w % 7) * 128;
  const int tid = threadIdx.x, wv = tid >> 6, lane = tid & 63;
  const int q4 = lane >> 4, c16 = lane & 15;
  constexpr int PLD = 136;

  __shared__ __attribute__((aligned(16))) u16 Qs[128*32];
  __shared__ __attribute__((aligned(16))) u16 Ks[128*32];
  __shared__ __attribute__((aligned(16))) u16 Vs[32*PLD];
  __shared__ __attribute__((aligned(16))) u16 Ps[4][32*PLD];

  {
    int r = tid >> 1, sg = (tid & 1) << 4;
    int row = q0 + r; if (row > NTOK-1) row = NTOK-1;
    const u16* src = qb + ((ll)(g*NTOK + row))*ldqk + h*32 + sg;
    *(uint4*)&Qs[r*32 + sg]     = *(const uint4*)src;
    *(uint4*)&Qs[r*32 + sg + 8] = *(const uint4*)(src + 8);
  }
  __syncthreads();

  bf16x8 qf[2];
  qf[0] = as_bf(*(const u16x8*)&Qs[(wv*32 +      c16)*32 + q4*8]);
  qf[1] = as_bf(*(const u16x8*)&Qs[(wv*32 + 16 + c16)*32 + q4*8]);

  float lsum[2][4] = {{0,0,0,0},{0,0,0,0}};
  f32x4 oacc[2][2];
  oacc[0][0] = (f32x4){0,0,0,0}; oacc[0][1] = (f32x4){0,0,0,0};
  oacc[1][0] = (f32x4){0,0,0,0}; oacc[1][1] = (f32x4){0,0,0,0};

  // per-thread staging slots (fixed across kt)
  const int rr  = tid >> 1, sg2 = (tid & 1) << 4;   // K: row rr, 16-col half sg2
  const int ve  = tid >> 3, vsg = (tid & 7) << 4;   // V: elem ve, 16-col chunk vsg
  uint4 kr0, kr1, vr0, vr1;                          // current tile (to write)
  uint4 nk0, nk1, nv0, nv1;                          // next tile (in flight)

  auto ldKV = [&](int kt2, uint4& a, uint4& b, uint4& c, uint4& d) {
    int row = kt2*128 + rr; if (row > NTOK-1) row = NTOK-1;
    const u16* src = kb + ((ll)(g*NTOK + row))*ldqk + h*32 + sg2;
    a = *(const uint4*)src;
    b = *(const uint4*)(src + 8);
    const u16* vsrc = vT + ((ll)(g*DM + h*32 + ve))*SPAD + kt2*128 + vsg;
    c = *(const uint4*)vsrc;
    d = *(const uint4*)(vsrc + 8);
  };

  ldKV(0, kr0, kr1, vr0, vr1);
  for (int kt = 0; kt < 7; ++kt) {
    const int k0 = kt * 128;
    if (kt) __syncthreads();            // previous compute done with Ks/Vs
    *(uint4*)&Ks[rr*32 + sg2]      = kr0;
    *(uint4*)&Ks[rr*32 + sg2 + 8]  = kr1;
    *(uint4*)&Vs[ve*PLD + vsg]     = vr0;
    *(uint4*)&Vs[ve*PLD + vsg + 8] = vr1;
    if (kt < 6) ldKV(kt + 1, nk0, nk1, nv0, nv1);   // in flight across compute
    __syncthreads();

    f32x4 s[2][8];
    #pragma unroll
    for (int i = 0; i < 2; ++i)
      #pragma unroll
      for (int j = 0; j < 8; ++j) s[i][j] = (f32x4){0,0,0,0};
    __builtin_amdgcn_s_setprio(1);
    #pragma unroll
    for (int j = 0; j < 8; ++j) {
      bf16x8 kf = as_bf(*(const u16x8*)&Ks[(j*16 + c16)*32 + q4*8]);
      s[0][j] = __builtin_amdgcn_mfma_f32_16x16x32_bf16(qf[0], kf, s[0][j], 0, 0, 0);
      s[1][j] = __builtin_amdgcn_mfma_f32_16x16x32_bf16(qf[1], kf, s[1][j], 0, 0, 0);
    }
    __builtin_amdgcn_s_setprio(0);
    if (kt == 6) {
      #pragma unroll
      for (int j = 0; j < 8; ++j) {
        if (k0 + j*16 + c16 >= NTOK) {
          #pragma unroll
          for (int r = 0; r < 4; ++r) { s[0][j][r] = -1e30f; s[1][j][r] = -1e30f; }
        }
      }
    }

    #pragma unroll
    for (int i = 0; i < 2; ++i)
      #pragma unroll
      for (int j = 0; j < 8; ++j)
        #pragma unroll
        for (int r = 0; r < 4; ++r) {
          float p = exp2f(s[i][j][r]);
          lsum[i][r] += p;
          unsigned u = __builtin_bit_cast(unsigned, p);
          Ps[wv][(i*16 + q4*4 + r)*PLD + j*16 + c16] = (u16)(u >> 16);
        }

    __builtin_amdgcn_s_setprio(1);
    #pragma unroll
    for (int kk = 0; kk < 4; ++kk) {
      bf16x8 af0 = as_bf(*(const u16x8*)&Ps[wv][(     c16)*PLD + kk*32 + q4*8]);
      bf16x8 af1 = as_bf(*(const u16x8*)&Ps[wv][(16 + c16)*PLD + kk*32 + q4*8]);
      bf16x8 b0  = as_bf(*(const u16x8*)&Vs[(     c16)*PLD + kk*32 + q4*8]);
      bf16x8 b1  = as_bf(*(const u16x8*)&Vs[(16 + c16)*PLD + kk*32 + q4*8]);
      oacc[0][0] = __builtin_amdgcn_mfma_f32_16x16x32_bf16(af0, b0, oacc[0][0], 0, 0, 0);
      oacc[0][1] = __builtin_amdgcn_mfma_f32_16x16x32_bf16(af0, b1, oacc[0][1], 0, 0, 0);
      oacc[1][0] = __builtin_amdgcn_mfma_f32_16x16x32_bf16(af1, b0, oacc[1][0], 0, 0, 0);
      oacc[1][1] = __builtin_amdgcn_mfma_f32_16x16x32_bf16(af1, b1, oacc[1][1], 0, 0, 0);
    }
    __builtin_amdgcn_s_setprio(0);

    kr0 = nk0; kr1 = nk1; vr0 = nv0; vr1 = nv1;
  }

  float linv[2][4];
  #pragma unroll
  for (int i = 0; i < 2; ++i)
    #pragma unroll
    for (int r = 0; r < 4; ++r) {
      float t = lsum[i][r];
      t += __shfl_xor(t, 1, 64);
      t += __shfl_xor(t, 2, 64);
      t += __shfl_xor(t, 4, 64);
      t += __shfl_xor(t, 8, 64);
      linv[i][r] = 1.f / t;
    }
  #pragma unroll
  for (int i = 0; i < 2; ++i)
    #pragma unroll
    for (int jn = 0; jn < 2; ++jn)
      #pragma unroll
      for (int r = 0; r < 4; ++r) {
        int row = q0 + wv*32 + i*16 + q4*4 + r;
        if (row < NTOK)
          attb[((ll)(g*NTOK + row))*DM + h*32 + jn*16 + c16] =
            f2b(oacc[i][jn][r] * linv[i][r]);
      }
}

// ------------------------------------------------------------------
__global__ __launch_bounds__(256) void ln_rows(const u16* __restrict__ in1,
                                               const u16* __restrict__ in2,
                                               int ld1, int ld2,
                                               const float* __restrict__ gamma,
                                               const float* __restrict__ beta,
                                               u16* __restrict__ out, int ldo, int Mrows)
{
  int row = blockIdx.x*4 + (threadIdx.x >> 6);
  int lane = threadIdx.x & 63;
  if (row >= Mrows) return;
  float xv[4];
  ushort4 a = *(const ushort4*)(in1 + (ll)row*ld1 + lane*4);
  xv[0]=b2f(a.x); xv[1]=b2f(a.y); xv[2]=b2f(a.z); xv[3]=b2f(a.w);
  if (in2) {
    ushort4 b = *(const ushort4*)(in2 + (ll)row*ld2 + lane*4);
    xv[0]-=b2f(b.x); xv[1]-=b2f(b.y); xv[2]-=b2f(b.z); xv[3]-=b2f(b.w);
  }
  float s = xv[0]+xv[1]+xv[2]+xv[3];
  #pragma unroll
  for (int o = 32; o > 0; o >>= 1) s += __shfl_xor(s, o, 64);
  float mean = s * (1.f/256.f);
  float d0=xv[0]-mean, d1=xv[1]-mean, d2=xv[2]-mean, d3=xv[3]-mean;
  float q = d0*d0 + d1*d1 + d2*d2 + d3*d3;
  #pragma unroll
  for (int o = 32; o > 0; o >>= 1) q += __shfl_xor(q, o, 64);
  float rstd = 1.f / sqrtf(q * (1.f/256.f) + 1e-5f);
  float4 gv = *(const float4*)(gamma + lane*4);
  float4 bb = *(const float4*)(beta  + lane*4);
  ushort4 o4;
  o4.x = f2b(d0*rstd*gv.x + bb.x);
  o4.y = f2b(d1*rstd*gv.y + bb.y);
  o4.z = f2b(d2*rstd*gv.z + bb.z);
  o4.w = f2b(d3*rstd*gv.w + bb.w);
  *(ushort4*)(out + (ll)row*ldo + lane*4) = o4;
}

// ------------------------------------------------------------------
__global__ __launch_bounds__(256) void final_combine(const u16* __restrict__ outF,
                                                     const float* __restrict__ meanp,
                                                     const float* __restrict__ stdp,
                                                     float* __restrict__ dout)
{
  int b = blockIdx.z;
  int c0 = blockIdx.x << 5, s0 = blockIdx.y << 5;
  __shared__ float tl[32][33];
  int tid = threadIdx.x;
  int si = tid & 31, r = tid >> 5;
  #pragma unroll
  for (int p = 0; p < 4; ++p) {
    int cl = r + (p << 3);
    int c = c0 + cl, s = s0 + si;
    float accv = 0.f;
    #pragma unroll
    for (int t = 0; t < 2; ++t) {
      int g = b*2 + t;
      if (c < ENC && s < SEQ) {
        float v = b2f(outF[((ll)(g*NTOK + c))*SEQ + s]);
        accv += 0.5f * (v * stdp[g*ENC + c] + meanp[g*ENC + c]);
      }
    }
    tl[cl][si] = accv;
  }
  __syncthreads();
  int ci = tid & 31;
  #pragma unroll
  for (int p = 0; p < 4; ++p) {
    int sl = r + (p << 3);
    int s = s0 + sl, c = c0 + ci;
    if (s < SEQ && c < ENC)
      dout[((ll)b*SEQ + s)*ENC + c] = tl[ci][sl];
  }
}

// ------------------------------------------------------------------
// Pipelined 64x64-tile NT GEMM, K-step 64 (two 32-wide panels),
// double-buffered LDS, raw s_barrier + counted vmcnt (T3/T4 recipe).
// Conflict-free XOR swizzle both sides (rule #21, verified r5: 0 conflicts).
// NB=1: modes 0 store / 1 gelu / 2 store+sub / 5 qkv. 32 KiB, 5 blk/CU.
// NB=2: 48 KiB, 3 blk/CU (used for W3/W4: N=256 keeps block count high).
// ------------------------------------------------------------------
template<int NB>
__global__ __launch_bounds__(256, NB == 1 ? 5 : 3) void gemm64(
    const u16* __restrict__ A, const u16* __restrict__ B0, const u16* __restrict__ B1,
    const float* __restrict__ bias0, const float* __restrict__ bias1,
    u16* __restrict__ C,
    const u16* __restrict__ aux1, u16* __restrict__ aux2, const u16* __restrict__ sub,
    int M, int N, int K, int lda, int ldb, int ldc, int ld1, int ld2, int ldsub, int mode)
{
  // [buf p][panel c] tiles of 64 rows x 32 cols, row-major ld=32
  __shared__ __attribute__((aligned(16))) u16 S[8192 * (1 + NB)];

  const int tid  = threadIdx.x;
  const int wv   = tid >> 6;
  const int lane = tid & 63;
  const int q4   = lane >> 4;
  const int c16  = lane & 15;

  const int w  = xcd_work();
  const int n0 = (w % gridDim.x) * 64;
  const int m0 = (w / gridDim.x) * 64;
  const int wm = (wv >> 1) * 32;
  const int wn = (wv & 1) * 32;

  // staging: 16 rows x 64 B per g2l; source chunk pre-swizzled so the
  // linear LDS write produces the XOR-swizzled layout
  const int lrow = lane >> 2;                                   // 0..15
  const int lcol = (((lane & 3) ^ ((lrow >> 1) & 3)) << 3);     // u16 offset

  int arow = m0 + wv*16 + lrow; if (arow >= M) arow = M-1;
  int brow = n0 + wv*16 + lrow; if (brow >= N) brow = N-1;
  const u16* pa  = A  + (ll)arow*lda + lcol;
  const u16* pb0 = B0 + (ll)brow*ldb + lcol;
  const u16* pb1 = (NB == 2) ? B1 + (ll)brow*ldb + lcol : nullptr;

  f32x4 acc0[2][2];
  f32x4 acc1[2][2];
  #pragma unroll
  for (int i = 0; i < 2; ++i)
    #pragma unroll
    for (int j = 0; j < 2; ++j) {
      acc0[i][j] = (f32x4){0,0,0,0};
      if constexpr (NB == 2) acc1[i][j] = (f32x4){0,0,0,0};
    }

  const int nk = K >> 6;
  auto issue = [&](int kt2, int p) {
    const int ko = kt2 * 64;
    #pragma unroll
    for (int c = 0; c < 2; ++c) {
      g2l(pa  + ko + c*32, &S[(p*2 + c)*2048 + (wv*16)*32]);
      g2l(pb0 + ko + c*32, &S[8192 + (p*2 + c)*2048 + (wv*16)*32]);
      if constexpr (NB == 2)
        g2l(pb1 + ko + c*32, &S[16384 + (p*2 + c)*2048 + (wv*16)*32]);
    }
  };

  issue(0, 0);
  for (int kt = 0; kt < nk; ++kt) {
    const int p = kt & 1;
    if (kt + 1 < nk) {
      issue(kt + 1, p ^ 1);
      // counted wait: just-issued loads (4 or 6) stay in flight
      if constexpr (NB == 1) asm volatile("s_waitcnt vmcnt(4)" ::: "memory");
      else                   asm volatile("s_waitcnt vmcnt(6)" ::: "memory");
    } else {
      asm volatile("s_waitcnt vmcnt(0)" ::: "memory");
    }
    __builtin_amdgcn_s_barrier();
    asm volatile("" ::: "memory");

    const int sw = ((q4 ^ ((c16 >> 1) & 3)) << 3);  // swizzled read chunk
    #pragma unroll
    for (int c = 0; c < 2; ++c) {
      const u16* as_ = &S[(p*2 + c)*2048];
      const u16* b0s = &S[8192 + (p*2 + c)*2048];
      bf16x8 af[2], bfv[2];
      #pragma unroll
      for (int i = 0; i < 2; ++i)
        af[i] = as_bf(*(const u16x8*)&as_[(wm + i*16 + c16)*32 + sw]);
      #pragma unroll
      for (int j = 0; j < 2; ++j)
        bfv[j] = as_bf(*(const u16x8*)&b0s[(wn + j*16 + c16)*32 + sw]);
      #pragma unroll
      for (int i = 0; i < 2; ++i)
        #pragma unroll
        for (int j = 0; j < 2; ++j)
          acc0[i][j] = __builtin_amdgcn_mfma_f32_16x16x32_bf16(af[i], bfv[j], acc0[i][j], 0, 0, 0);
      if constexpr (NB == 2) {
        const u16* b1s = &S[16384 + (p*2 + c)*2048];
        bf16x8 b1v[2];
        #pragma unroll
        for (int j = 0; j < 2; ++j)
          b1v[j] = as_bf(*(const u16x8*)&b1s[(wn + j*16 + c16)*32 + sw]);
        #pragma unroll
        for (int i = 0; i < 2; ++i)
          #pragma unroll
          for (int j = 0; j < 2; ++j)
            acc1[i][j] = __builtin_amdgcn_mfma_f32_16x16x32_bf16(af[i], b1v[j], acc1[i][j], 0, 0, 0);
      }
    }

    asm volatile("s_waitcnt lgkmcnt(0)" ::: "memory");
    __builtin_amdgcn_s_barrier();
  }

  #pragma unroll
  for (int i = 0; i < 2; ++i) {
    #pragma unroll
    for (int j = 0; j < 2; ++j) {
      int n = n0 + wn + j*16 + c16;
      if (n >= N) continue;
      float bv0 = bias0 ? bias0[n] : 0.f;
      float bv1 = (NB == 2) ? bias1[n] : 0.f;
      int mb = m0 + wm + i*16 + q4*4;
      #pragma unroll
      for (int r = 0; r < 4; ++r) {
        int m = mb + r;
        if (m >= M) continue;
        ll ci = (ll)m*ldc + n;
        if constexpr (NB == 2) {
          float z5 = acc0[i][j][r] + bv0;
          float z6 = acc1[i][j][r] + bv1;
          float v = z6 / (1.f + expf(-z5));
          if (sub) v -= b2f(sub[(ll)m*ldsub + n]);
          C[ci] = f2b(v);
        } else {
          float x = acc0[i][j][r] + bv0;
          if (mode == 0) {
            C[ci] = f2b(x);
          } else if (mode == 1) {
            C[ci] = f2b(0.5f * x * (1.f + erff(x * 0.70710678118654752f)));
          } else if (mode == 5) {
            C[ci] = f2b(n < 256 ? x * SC2 : x);
          } else { // mode 2
            C[ci] = f2b(x);
            float xl = b2f(aux1[(ll)m*ld1 + n]);
            aux2[(ll)m*ld2 + n] = f2b(xl - x);
          }
        }
      }
    }
  }
}

// ------------------------------------------------------------------
// 128x64-tile dual-B NT GEMM for W5/W6, BK=32, double-buffered.
// r6-measured best for this op (61.0 us). r2-r9 exhausted the schedule
// axes (pipelining r3, conflicts r5, reuse-ratio r6/r8, no-LDS r7,
// prefetch depth r9) -- all land 61-84 us; this config is the min.
// Plateau is the structure family's known small-shape limit (m102
// curve); do NOT retune -- a gain here needs the 8-phase 256^2 port.
// Waves 2Mx2N, wave tile 64x32 of BOTH outputs. LDS 32 KiB, 4 blk/CU.
// C = sig(A B0^T + b0) * (A B1^T + b1) [- sub].
// ------------------------------------------------------------------
__global__ __launch_bounds__(256, 4) void gemm128d(
    const u16* __restrict__ A, const u16* __restrict__ B0, const u16* __restrict__ B1,
    const float* __restrict__ bias0, const float* __restrict__ bias1,
    u16* __restrict__ C, const u16* __restrict__ sub,
    int M, int N, int K, int lda, int ldb, int ldc, int ldsub)
{
  // A: 2 bufs x (128x32) = 8192 u16; B0: 2 x (64x32) = 4096; B1: 4096
  __shared__ __attribute__((aligned(16))) u16 S[16384];

  const int tid  = threadIdx.x;
  const int wv   = tid >> 6;
  const int lane = tid & 63;
  const int q4   = lane >> 4;
  const int c16  = lane & 15;

  const int w  = xcd_work();
  const int n0 = (w % gridDim.x) * 64;
  const int m0 = (w / gridDim.x) * 128;
  const int wm = (wv >> 1) * 64;
  const int wn = (wv & 1) * 32;

  const int lrow = lane >> 2;                                   // 0..15
  const int lcol = (((lane & 3) ^ ((lrow >> 1) & 3)) << 3);     // pre-swizzled src

  int ar0 = m0 + wv*32 + lrow;      if (ar0 >= M) ar0 = M-1;
  int ar1 = m0 + wv*32 + 16 + lrow; if (ar1 >= M) ar1 = M-1;
  int br  = n0 + wv*16 + lrow;      if (br  >= N) br  = N-1;
  const u16* pa0 = A  + (ll)ar0*lda + lcol;
  const u16* pa1 = A  + (ll)ar1*lda + lcol;
  const u16* pb0 = B0 + (ll)br*ldb + lcol;
  const u16* pb1 = B1 + (ll)br*ldb + lcol;

  f32x4 acc0[4][2], acc1[4][2];
  #pragma unroll
  for (int i = 0; i < 4; ++i)
    #pragma unroll
    for (int j = 0; j < 2; ++j) {
      acc0[i][j] = (f32x4){0,0,0,0};
      acc1[i][j] = (f32x4){0,0,0,0};
    }

  const int nk = K >> 5;
  auto issue = [&](int kt2, int p) {
    const int ko = kt2 * 32;
    g2l(pa0 + ko, &S[p*4096 + (wv*32)*32]);
    g2l(pa1 + ko, &S[p*4096 + (wv*32 + 16)*32]);
    g2l(pb0 + ko, &S[8192  + p*2048 + (wv*16)*32]);
    g2l(pb1 + ko, &S[12288 + p*2048 + (wv*16)*32]);
  };

  issue(0, 0);
  for (int kt = 0; kt < nk; ++kt) {
    const int p = kt & 1;
    if (kt + 1 < nk) {
      issue(kt + 1, p ^ 1);
      asm volatile("s_waitcnt vmcnt(4)" ::: "memory");  // 4 new stay in flight
    } else {
      asm volatile("s_waitcnt vmcnt(0)" ::: "memory");
    }
    __builtin_amdgcn_s_barrier();
    asm volatile("" ::: "memory");

    const int sw = ((q4 ^ ((c16 >> 1) & 3)) << 3);
    const u16* as_ = &S[p*4096];
    const u16* b0s = &S[8192  + p*2048];
    const u16* b1s = &S[12288 + p*2048];
    bf16x8 af[4], b0v[2], b1v[2];
    #pragma unroll
    for (int i = 0; i < 4; ++i)
      af[i] = as_bf(*(const u16x8*)&as_[(wm + i*16 + c16)*32 + sw]);
    #pragma unroll
    for (int j = 0; j < 2; ++j) {
      b0v[j] = as_bf(*(const u16x8*)&b0s[(wn + j*16 + c16)*32 + sw]);
      b1v[j] = as_bf(*(const u16x8*)&b1s[(wn + j*16 + c16)*32 + sw]);
    }
    #pragma unroll
    for (int i = 0; i < 4; ++i)
      #pragma unroll
      for (int j = 0; j < 2; ++j) {
        acc0[i][j] = __builtin_amdgcn_mfma_f32_16x16x32_bf16(af[i], b0v[j], acc0[i][j], 0, 0, 0);
        acc1[i][j] = __builtin_amdgcn_mfma_f32_16x16x32_bf16(af[i], b1v[j], acc1[i][j], 0, 0, 0);
      }

    asm volatile("s_waitcnt lgkmcnt(0)" ::: "memory");
    __builtin_amdgcn_s_barrier();
  }

  #pragma unroll
  for (int i = 0; i < 4; ++i) {
    #pragma unroll
    for (int j = 0; j < 2; ++j) {
      int n = n0 + wn + j*16 + c16;
      if (n >= N) continue;
      float bv0 = bias0[n], bv1 = bias1[n];
      int mb = m0 + wm + i*16 + q4*4;
      #pragma unroll
      for (int r = 0; r < 4; ++r) {
        int m = mb + r;
        if (m >= M) continue;
        float z5 = acc0[i][j][r] + bv0;
        float z6 = acc1[i][j][r] + bv1;
        float v = z6 / (1.f + expf(-z5));
        if (sub) v -= b2f(sub[(ll)m*ldsub + n]);
        C[(ll)m*ldc + n] = f2b(v);
      }
    }
  }
}

// ------------------------------------------------------------------
extern "C" void kernel_launch(void* const* d_in, const int* in_sizes, int n_in,
                              void* d_out, int out_size, void* d_ws, size_t ws_size,
                              hipStream_t stream)
{
  (void)in_sizes; (void)n_in; (void)out_size; (void)ws_size;
  const float* x    = (const float*)d_in[0];
  const float* xm   = (const float*)d_in[1];
  const float* embw = (const float*)d_in[4];
  const float* embb = (const float*)d_in[5];
  const float* Wqf  = (const float*)d_in[6];
  const float* Wkf  = (const float*)d_in[7];
  const float* Wvf  = (const float*)d_in[8];
  const float* Wof  = (const float*)d_in[9];
  const float* W3f  = (const float*)d_in[10];
  const float* W4f  = (const float*)d_in[11];
  const float* bq   = (const float*)d_in[12];
  const float* bk   = (const float*)d_in[13];
  const float* bv   = (const float*)d_in[14];
  const float* bo   = (const float*)d_in[15];
  const float* b3   = (const float*)d_in[16];
  const float* b4   = (const float*)d_in[17];
  const float* W1f  = (const float*)d_in[18];
  const float* b1   = (const float*)d_in[19];
  const float* W2f  = (const float*)d_in[20];
  const float* b2   = (const float*)d_in[21];
  const float* W5f  = (const float*)d_in[22];
  const float* b5   = (const float*)d_in[23];
  const float* W6f  = (const float*)d_in[24];
  const float* b6   = (const float*)d_in[25];
  const float* ln1g = (const float*)d_in[26];
  const float* ln1b = (const float*)d_in[27];
  const float* ln2g = (const float*)d_in[28];
  const float* ln2b = (const float*)d_in[29];

  u8* ws = (u8*)d_ws;
  size_t off = 0;
  auto alloc = [&](size_t bytes) -> void* {
    void* ptr = ws + off;
    off = (off + bytes + 255) & ~(size_t)255;
    return ptr;
  };
  float* meanp = (float*)alloc((size_t)G16*ENC*4);
  float* stdp  = (float*)alloc((size_t)G16*ENC*4);
  float* partp = (float*)alloc((size_t)G16*TCH*1024*2*4);
  u16* xin   = (u16*)alloc((size_t)G16*NTOK*KPAD*2);
  u16* wp    = (u16*)alloc((size_t)DM*KPAD*2);
  const int nWsm = 2*DM*DM;
  const int nWff = 2*512*DM;
  const int nW56 = 2*SEQ*512;
  u16* Wqkv = (u16*)alloc((size_t)2*768*256*2);
  u16* Wo = (u16*)alloc((size_t)nWsm*2);
  u16* W3 = (u16*)alloc((size_t)nWsm*2);
  u16* W4 = (u16*)alloc((size_t)nWsm*2);
  u16* W1 = (u16*)alloc((size_t)nWff*2);
  u16* W2 = (u16*)alloc((size_t)nWff*2);
  u16* W5 = (u16*)alloc((size_t)nW56*2);
  u16* W6 = (u16*)alloc((size_t)nW56*2);
  float* bqkv = (float*)alloc((size_t)2*768*4);
  u16* hb    = (u16*)alloc((size_t)MTOT*DM*2);
  u16* qkvb  = (u16*)alloc((size_t)MTOT*768*2);
  u16* vT    = (u16*)alloc((size_t)G16*DM*SPAD*2);
  u16* attb  = (u16*)alloc((size_t)MTOT*DM*2);
  u16* catb  = (u16*)alloc((size_t)MTOT*512*2);
  u16* xlnb  = (u16*)alloc((size_t)MTOT*DM*2);
  u16* t1b   = (u16*)alloc((size_t)MTOT*512*2);
  u16* xsb   = (u16*)alloc((size_t)MTOT*DM*2);
  u16* hhb   = (u16*)alloc((size_t)MTOT*DM*2);
  u16* out0b = (u16*)alloc((size_t)MTOT*SEQ*2);
  u16* outFb = (u16*)alloc((size_t)MTOT*SEQ*2);

  // pipelined 64x64 single-B gemm
  auto gemm64_1 = [&](const u16* A, int lda, const u16* B, int ldb, const float* bias,
                      u16* C, int ldc, int M, int N, int K, int mode,
                      const u16* a1, int ld1, u16* a2, int ld2) {
    dim3 grid((N + 63) / 64, (M + 63) / 64, 1);
    gemm64<1><<<grid, 256, 0, stream>>>(A, B, nullptr, bias, nullptr, C, a1, a2, nullptr,
                                        M, N, K, lda, ldb, ldc, ld1, ld2, 0, mode);
  };
  // pipelined 64x64 dual-B gemm (glu) -- W3/W4 (N=256)
  auto gemm64_2 = [&](const u16* A, int lda, const u16* B0p, const u16* B1p, int ldb,
                      const float* bias0, const float* bias1, u16* C, int ldc,
                      const u16* sub, int ldsub, int M, int N, int K) {
    dim3 grid((N + 63) / 64, (M + 63) / 64, 1);
    gemm64<2><<<grid, 256, 0, stream>>>(A, B0p, B1p, bias0, bias1, C, nullptr, nullptr, sub,
                                        M, N, K, lda, ldb, ldc, 0, 0, ldsub, 0);
  };
  // 128x64 dual-B gemm (r6 best) -- W5/W6 (N=720, K=512)
  auto gemmD128 = [&](const u16* A, int lda, const u16* B0p, const u16* B1p, int ldb,
                      const float* bias0, const float* bias1, u16* C, int ldc,
                      const u16* sub, int ldsub, int M, int N, int K) {
    dim3 grid((N + 63) / 64, (M + 127) / 128, 1);
    gemm128d<<<grid, 256, 0, stream>>>(A, B0p, B1p, bias0, bias1, C, sub,
                                       M, N, K, lda, ldb, ldc, ldsub);
  };

  // weight conversion: one launch, 10 jobs
  CvtJobs J{};
  int nj = 0;
  auto addjob = [&](const float* s, u16* d, int n, int per, ll stride) {
    J.src[nj] = s; J.dst[nj] = d; J.n[nj] = n; J.per[nj] = per; J.stride[nj] = stride; nj++;
  };
  addjob(Wqf, Wqkv,           nWsm, 65536, 196608);
  addjob(Wkf, Wqkv + 65536,   nWsm, 65536, 196608);
  addjob(Wvf, Wqkv + 131072,  nWsm, 65536, 196608);
  addjob(Wof, Wo, nWsm, 0, 0);
  addjob(W3f, W3, nWsm, 0, 0);
  addjob(W4f, W4, nWsm, 0, 0);
  addjob(W1f, W1, nWff, 0, 0);
  addjob(W2f, W2, nWff, 0, 0);
  addjob(W5f, W5, nW56, 0, 0);
  addjob(W6f, W6, nW56, 0, 0);
  cvt_multi<<<dim3(512, 10), 256, 0, stream>>>(J);
  pack_bqkv<<<6, 256, 0, stream>>>(bq, bk, bv, bqkv);

  stats_part<<<dim3(4, TCH, 16), 256, 0, stream>>>(x, (float2*)partp);
  stats_reduce<<<64, 256, 0, stream>>>((const float2*)partp, meanp, stdp);
  build_xin<<<dim3(28, 24, 16), 256, 0, stream>>>(x, xm, meanp, stdp, xin);
  pack_embedw<<<256, 256, 0, stream>>>(embw, wp);

  // h = xin @ embed_w^T + embed_b
  gemm64_1(xin, KPAD, wp, KPAD, embb, hb, DM, MTOT, DM, KPAD, 0, nullptr, 0, nullptr, 0);

  for (int l = 0; l < 2; ++l) {
    const ll wOff = (ll)l * DM * DM;
    // fused qkv (q pre-scaled by scale*log2e)
    gemm64_1(hb, DM, Wqkv + (ll)l*768*256, 256, bqkv + l*768, qkvb, 768,
             MTOT, 768, DM, 5, nullptr, 0, nullptr, 0);
    transpose_v<<<dim3(8, 28, 16), 256, 0, stream>>>(qkvb + 512, 768, vT);

    flash_attn<<<dim3(7, 128), 256, 0, stream>>>(qkvb, qkvb + 256, 768, vT, attb);

    // x_att -> cat[:, 0:256]
    gemm64_1(attb, DM, Wo + wOff, DM, bo + l*DM, catb, 512, MTOT, DM, DM, 0, nullptr, 0, nullptr, 0);
    // x_ln = LN(h - x_att)
    ln_rows<<<MTOT/4, 256, 0, stream>>>(hb, catb, DM, 512, ln1g + l*DM, ln1b + l*DM, xlnb, DM, MTOT);
    // t1 = gelu(x_ln @ W1^T + b1)
    gemm64_1(xlnb, DM, W1 + (ll)l*512*DM, DM, b1 + l*512, t1b, 512, MTOT, 512, DM, 1, nullptr, 0, nullptr, 0);
    // y -> cat[:, 256:512]; xs = x_ln - y
    gemm64_1(t1b, 512, W2 + (ll)l*DM*512, 512, b2 + l*DM, catb + 256, 512, MTOT, DM, 512, 2, xlnb, DM, xsb, DM);
    // hh = sigmoid(xs W3^T + b3) * (xs W4^T + b4)
    gemm64_2(xsb, DM, W3 + wOff, W4 + wOff, DM, b3 + l*DM, b4 + l*DM, hhb, DM,
             nullptr, 0, MTOT, DM, DM);
    // h = LN(hh)
    ln_rows<<<MTOT/4, 256, 0, stream>>>(hhb, nullptr, DM, 0, ln2g + l*DM, ln2b + l*DM, hb, DM, MTOT);
    // out = sigmoid(cat W5^T + b5) * (cat W6^T + b6)  [- out0 on layer 1]
    if (l == 0)
      gemmD128(catb, 512, W5 + (ll)l*SEQ*512, W6 + (ll)l*SEQ*512, 512,
               b5 + l*SEQ, b6 + l*SEQ, out0b, SEQ, nullptr, 0, MTOT, SEQ, 512);
    else
      gemmD128(catb, 512, W5 + (ll)l*SEQ*512, W6 + (ll)l*SEQ*512, 512,
               b5 + l*SEQ, b6 + l*SEQ, outFb, SEQ, out0b, SEQ, MTOT, SEQ, 512);
  }

  final_combine<<<dim3(27, 23, 8), 256, 0, stream>>>(outFb, meanp, stdp, (float*)d_out);
}